// Round 2
// baseline (2070.141 us; speedup 1.0000x reference)
//
#include <hip/hip_runtime.h>
#include <math.h>

#define NN 50000
#define NE 400000
#define DDIM 128
#define NHEAD 4
#define NRAD 50
#define NGRAPH 100
#define TEMB 32
#define DOUT 512
#define CUTF 6.0f
#define PI_F 3.14159265358979323846f

typedef unsigned int uint;
typedef unsigned short ushort;

// ---------------- helpers ----------------

__device__ __forceinline__ float gelu_tanh(float v) {
  float u = 0.7978845608028654f * (v + 0.044715f * v * v * v);
  return 0.5f * v * (1.0f + tanhf(u));
}

__device__ __forceinline__ ushort f2bf(float f) {  // RNE
  uint u = __float_as_uint(f);
  uint r = (u + 0x7fffu + ((u >> 16) & 1u)) >> 16;
  return (ushort)r;
}

__global__ void k_fill_f(float* p, float v, int n) {
  int i = blockIdx.x * blockDim.x + threadIdx.x;
  if (i < n) p[i] = v;
}
__global__ void k_fill_i(int* p, int v, int n) {
  int i = blockIdx.x * blockDim.x + threadIdx.x;
  if (i < n) p[i] = v;
}

// ---------------- init: x = [emb[at], pos] @ W_init + b ----------------

__global__ void k_init(const float* __restrict__ pos, const int* __restrict__ at,
                       const float* __restrict__ emb, const float* __restrict__ W,
                       const float* __restrict__ b, float* __restrict__ x) {
  int idx = blockIdx.x * blockDim.x + threadIdx.x;
  if (idx >= NN * DDIM) return;
  int n = idx >> 7, c = idx & 127;
  const float* er = emb + (size_t)at[n] * TEMB;
  float acc = b[c];
#pragma unroll
  for (int t = 0; t < TEMB; ++t) acc = fmaf(er[t], W[t * DDIM + c], acc);
  acc = fmaf(pos[n * 3 + 0], W[(TEMB + 0) * DDIM + c], acc);
  acc = fmaf(pos[n * 3 + 1], W[(TEMB + 1) * DDIM + c], acc);
  acc = fmaf(pos[n * 3 + 2], W[(TEMB + 2) * DDIM + c], acc);
  x[idx] = acc;
}

// ---------------- per-edge distance ----------------

__global__ void k_dist(const float* __restrict__ pos, const int* __restrict__ ei,
                       float* __restrict__ de) {
  int e = blockIdx.x * blockDim.x + threadIdx.x;
  if (e >= NE) return;
  int s = ei[e], t = ei[NE + e];
  float dx = pos[s * 3 + 0] - pos[t * 3 + 0] + 1e-8f;
  float dy = pos[s * 3 + 1] - pos[t * 3 + 1] + 1e-8f;
  float dz = pos[s * 3 + 2] - pos[t * 3 + 2] + 1e-8f;
  de[e] = sqrtf(dx * dx + dy * dy + dz * dz);
}

// ---------------- CSR build: hist -> scan -> scatter ----------------

__global__ void k_hist(const int* __restrict__ ei, int* __restrict__ deg) {
  int e = blockIdx.x * blockDim.x + threadIdx.x;
  if (e >= NE) return;
  atomicAdd(&deg[ei[NE + e]], 1);
}

// single block, 1024 threads: exclusive scan of deg -> rowptr (and cursor copy)
__global__ void k_scan(const int* __restrict__ deg, int* __restrict__ rowptr,
                       int* __restrict__ cursor) {
  __shared__ int part[1024];
  const int CHUNK = (NN + 1023) / 1024;  // 49
  int t = threadIdx.x;
  int lo = t * CHUNK, hi = lo + CHUNK;
  if (hi > NN) hi = NN;
  int s = 0;
  for (int i = lo; i < hi; ++i) s += deg[i];
  part[t] = s;
  __syncthreads();
  for (int off = 1; off < 1024; off <<= 1) {
    int v = (t >= off) ? part[t - off] : 0;
    __syncthreads();
    part[t] += v;
    __syncthreads();
  }
  int run = (t == 0) ? 0 : part[t - 1];
  for (int i = lo; i < hi; ++i) {
    rowptr[i] = run;
    cursor[i] = run;
    run += deg[i];
  }
  if (t == 1023) rowptr[NN] = part[1023];
}

__global__ void k_scatter(const int* __restrict__ ei, int* __restrict__ cursor,
                          int* __restrict__ eids) {
  int e = blockIdx.x * blockDim.x + threadIdx.x;
  if (e >= NE) return;
  int idx = atomicAdd(&cursor[ei[NE + e]], 1);
  eids[idx] = e;
}

// ---------------- generic 128x128 GEMM: out = act(A@W + bias) (+ resid) ----------------
// block 256: 32 rows x 128 cols, 4x4 register tile per thread.

#define GEMM_ROWS 32
template <bool BIAS, bool ACT_GELU, bool RESID, bool OUTBF>
__global__ __launch_bounds__(256, 2) void k_gemm(
    const float* __restrict__ A, const float* __restrict__ W,
    const float* __restrict__ bias, const float* __restrict__ resid,
    void* __restrict__ outp, int nrows) {
  __shared__ float Wl[DDIM * DDIM];        // 64 KB, [c][k^swz]
  __shared__ float Al[GEMM_ROWS * DDIM];   // 16 KB
  const int tid = threadIdx.x;
  const int r0 = blockIdx.x * GEMM_ROWS;

  for (int i = tid; i < DDIM * (DDIM / 4); i += 256) {
    int k = i >> 5;
    int c4 = (i & 31) << 2;
    float4 wv = *(const float4*)&W[k * DDIM + c4];
    float vals[4] = {wv.x, wv.y, wv.z, wv.w};
#pragma unroll
    for (int j = 0; j < 4; ++j) {
      int c = c4 + j;
      Wl[c * DDIM + (k ^ (((c >> 2) & 7) << 2))] = vals[j];
    }
  }
  for (int i = tid; i < GEMM_ROWS * (DDIM / 4); i += 256) {
    int r = i >> 5;
    int k4 = (i & 31) << 2;
    int gr = r0 + r;
    float4 av = (gr < nrows) ? *(const float4*)&A[(size_t)gr * DDIM + k4]
                             : make_float4(0.f, 0.f, 0.f, 0.f);
    *(float4*)&Al[r * DDIM + k4] = av;
  }
  __syncthreads();

  const int cidx = tid & 31;
  const int ridx = tid >> 5;
  const int cbase = cidx << 2;
  const int swz = (cidx & 7) << 2;
  float acc[4][4];
#pragma unroll
  for (int i = 0; i < 4; ++i)
#pragma unroll
    for (int j = 0; j < 4; ++j) acc[i][j] = 0.f;

  for (int k = 0; k < DDIM; k += 4) {
    float4 a[4], w[4];
#pragma unroll
    for (int i = 0; i < 4; ++i) a[i] = *(float4*)&Al[(ridx * 4 + i) * DDIM + k];
#pragma unroll
    for (int j = 0; j < 4; ++j) w[j] = *(float4*)&Wl[(cbase + j) * DDIM + (k ^ swz)];
#pragma unroll
    for (int i = 0; i < 4; ++i)
#pragma unroll
      for (int j = 0; j < 4; ++j) {
        acc[i][j] = fmaf(a[i].x, w[j].x, acc[i][j]);
        acc[i][j] = fmaf(a[i].y, w[j].y, acc[i][j]);
        acc[i][j] = fmaf(a[i].z, w[j].z, acc[i][j]);
        acc[i][j] = fmaf(a[i].w, w[j].w, acc[i][j]);
      }
  }

#pragma unroll
  for (int i = 0; i < 4; ++i) {
    int r = r0 + ridx * 4 + i;
    if (r >= nrows) continue;
    float v[4];
    float4 rv;
    if (RESID) rv = *(const float4*)&resid[(size_t)r * DDIM + cbase];
#pragma unroll
    for (int j = 0; j < 4; ++j) {
      float vv = acc[i][j];
      if (BIAS) vv += bias[cbase + j];
      if (ACT_GELU) vv = gelu_tanh(vv);
      v[j] = vv;
    }
    if (RESID) { v[0] += rv.x; v[1] += rv.y; v[2] += rv.z; v[3] += rv.w; }
    if (OUTBF) {
      ushort4 pk = {f2bf(v[0]), f2bf(v[1]), f2bf(v[2]), f2bf(v[3])};
      *(ushort4*)&((ushort*)outp)[(size_t)r * DDIM + cbase] = pk;
    } else {
      float4 pk = {v[0], v[1], v[2], v[3]};
      *(float4*)&((float*)outp)[(size_t)r * DDIM + cbase] = pk;
    }
  }
}

// ---------------- fused edge attention: per-node flash-style aggregation ----------------
// one wave (64 lanes) per node; lane t owns dims 2t, 2t+1 (head = t>>4).
// online softmax over incoming edges; ef = rb@We only when d < cutoff.

__device__ __forceinline__ float rbf_fill(float d, int j) {
  const float step = CUTF / (NRAD - 1);
  const float gamma = (NRAD / CUTF) * (NRAD / CUTF);
  float mu = j * step;
  float dm = d - mu;
  float env = 0.5f * (cosf(PI_F * d / CUTF) + 1.0f);
  return expf(-gamma * dm * dm) * env;
}

__global__ __launch_bounds__(256) void k_attn(
    const float* __restrict__ qn, const ushort* __restrict__ kn,
    const ushort* __restrict__ vn, const float* __restrict__ de,
    const int* __restrict__ ei, const int* __restrict__ rowptr,
    const int* __restrict__ eids, const float* __restrict__ We,
    float* __restrict__ msg) {
  const int n = (blockIdx.x * 256 + threadIdx.x) >> 6;  // node = global wave id
  const int t = threadIdx.x & 63;
  float2 q = *(const float2*)&qn[(size_t)n * DDIM + t * 2];
  const int start = rowptr[n], end = rowptr[n + 1];

  float m = -INFINITY, s = 0.f, a0 = 0.f, a1 = 0.f;
  for (int i = start; i < end; ++i) {
    int e = eids[i];
    int src = ei[e];
    float d = de[e];
    uint ku = *(const uint*)&kn[(size_t)src * DDIM + t * 2];
    uint vu = *(const uint*)&vn[(size_t)src * DDIM + t * 2];
    float k0 = __uint_as_float(ku << 16);
    float k1 = __uint_as_float(ku & 0xffff0000u);
    float v0 = __uint_as_float(vu << 16);
    float v1 = __uint_as_float(vu & 0xffff0000u);
    float ef0 = 0.f, ef1 = 0.f;
    if (d < CUTF) {
      float rbm = rbf_fill(d, t);
#pragma unroll
      for (int j = 0; j < NRAD; ++j) {
        float rbj = __shfl(rbm, j);
        float2 w = *(const float2*)&We[j * DDIM + t * 2];
        ef0 = fmaf(rbj, w.x, ef0);
        ef1 = fmaf(rbj, w.y, ef1);
      }
    }
    float p = q.x * (k0 + ef0) + q.y * (k1 + ef1);
    p += __shfl_xor(p, 8);
    p += __shfl_xor(p, 4);
    p += __shfl_xor(p, 2);
    p += __shfl_xor(p, 1);
    p *= 0.17677669529663687f;  // 1/sqrt(32)
    float mn = fmaxf(m, p);
    float cold = expf(m - mn);
    float w = expf(p - mn);
    s = s * cold + w;
    a0 = a0 * cold + w * (v0 + ef0);
    a1 = a1 * cold + w * (v1 + ef1);
    m = mn;
  }
  float inv = 1.0f / (s + 1e-9f);
  float2 o = {a0 * inv, a1 * inv};
  *(float2*)&msg[(size_t)n * DDIM + t * 2] = o;
}

// ---------------- layernorm (per node, 1 wave) ----------------

__global__ void k_ln(const float* __restrict__ x, const float* __restrict__ g,
                     const float* __restrict__ b, float* __restrict__ h) {
  int n = blockIdx.x;
  int t = threadIdx.x;  // 64
  float v0 = x[(size_t)n * DDIM + t];
  float v1 = x[(size_t)n * DDIM + 64 + t];
  float s = v0 + v1;
  float ss = v0 * v0 + v1 * v1;
#pragma unroll
  for (int m = 32; m >= 1; m >>= 1) {
    s += __shfl_xor(s, m);
    ss += __shfl_xor(ss, m);
  }
  float mean = s * (1.0f / DDIM);
  float var = ss * (1.0f / DDIM) - mean * mean;
  float inv = rsqrtf(var + 1e-5f);
  h[(size_t)n * DDIM + t] = (v0 - mean) * inv * g[t] + b[t];
  h[(size_t)n * DDIM + 64 + t] = (v1 - mean) * inv * g[64 + t] + b[64 + t];
}

// ---------------- graph sum (batch is sorted) ----------------

__global__ void k_graphsum(const float* __restrict__ x, const int* __restrict__ batch,
                           float* __restrict__ g) {
  int t = threadIdx.x;  // 128 dims
  int n0 = blockIdx.x * 512;
  int nend = n0 + 512;
  if (nend > NN) nend = NN;
  if (n0 >= NN) return;
  float acc = 0.f;
  int cur = batch[n0];
  for (int n = n0; n < nend; ++n) {
    int bb = batch[n];
    if (bb != cur) {
      atomicAdd(&g[(size_t)cur * DDIM + t], acc);
      acc = 0.f;
      cur = bb;
    }
    acc += x[(size_t)n * DDIM + t];
  }
  atomicAdd(&g[(size_t)cur * DDIM + t], acc);
}

// ---------------- output projection ----------------

__global__ void k_out(const float* __restrict__ g, const float* __restrict__ W,
                      const float* __restrict__ b, float* __restrict__ out) {
  int idx = blockIdx.x * blockDim.x + threadIdx.x;
  if (idx >= NGRAPH * DOUT) return;
  int r = idx / DOUT, c = idx % DOUT;
  float acc = b[c];
#pragma unroll 8
  for (int k = 0; k < DDIM; ++k) acc = fmaf(g[r * DDIM + k], W[k * DOUT + c], acc);
  out[idx] = acc;
}

// ---------------- launch ----------------

extern "C" void kernel_launch(void* const* d_in, const int* in_sizes, int n_in,
                              void* d_out, int out_size, void* d_ws, size_t ws_size,
                              hipStream_t stream) {
  const float* pos = (const float*)d_in[0];
  const int* at = (const int*)d_in[1];
  const int* ei = (const int*)d_in[2];
  const int* batch = (const int*)d_in[3];
  const float* emb = (const float*)d_in[4];
  const float* W_init = (const float*)d_in[5];
  const float* b_init = (const float*)d_in[6];
  const float* Wq = (const float*)d_in[7];
  const float* Wk = (const float*)d_in[8];
  const float* Wv = (const float*)d_in[9];
  const float* We = (const float*)d_in[10];
  const float* Wo = (const float*)d_in[11];
  const float* Wm1 = (const float*)d_in[12];
  const float* bm1 = (const float*)d_in[13];
  const float* Wm2 = (const float*)d_in[14];
  const float* bm2 = (const float*)d_in[15];
  const float* ln_g = (const float*)d_in[16];
  const float* ln_b = (const float*)d_in[17];
  const float* W_out = (const float*)d_in[18];
  const float* b_out = (const float*)d_in[19];
  float* out = (float*)d_out;

  const size_t ND = (size_t)NN * DDIM;  // 6.4M
  float* x = (float*)d_ws;              // f32 ND
  float* qn = x + ND;                   // f32 ND (later: hb)
  float* msg = qn + ND;                 // f32 ND (later: h2)
  ushort* knb = (ushort*)(msg + ND);    // bf16 ND
  ushort* vnb = knb + ND;               // bf16 ND
  float* de = (float*)(vnb + ND);       // f32 NE
  int* deg = (int*)(de + NE);           // NN
  int* cursor = deg + NN;               // NN
  int* rowptr = cursor + NN;            // NN+1 (+pad)
  int* eids = rowptr + NN + 64;         // NE
  float* gb = (float*)(eids + NE);      // NG*DDIM
  // total ~106 MB

  float* hb = qn;
  float* h2 = msg;

  // ---- static per-call precompute ----
  k_init<<<(NN * DDIM + 255) / 256, 256, 0, stream>>>(pos, at, emb, W_init, b_init, x);
  k_dist<<<(NE + 255) / 256, 256, 0, stream>>>(pos, ei, de);
  k_fill_i<<<(NN + 255) / 256, 256, 0, stream>>>(deg, 0, NN);
  k_hist<<<(NE + 255) / 256, 256, 0, stream>>>(ei, deg);
  k_scan<<<1, 1024, 0, stream>>>(deg, rowptr, cursor);
  k_scatter<<<(NE + 255) / 256, 256, 0, stream>>>(ei, cursor, eids);

  const int gemm_grid = (NN + GEMM_ROWS - 1) / GEMM_ROWS;
  for (int l = 0; l < 2; ++l) {
    const float* Wq_l = Wq + (size_t)l * DDIM * DDIM;
    const float* Wk_l = Wk + (size_t)l * DDIM * DDIM;
    const float* Wv_l = Wv + (size_t)l * DDIM * DDIM;
    const float* We_l = We + (size_t)l * NRAD * DDIM;
    const float* Wo_l = Wo + (size_t)l * DDIM * DDIM;
    const float* Wm1_l = Wm1 + (size_t)l * DDIM * DDIM;
    const float* Wm2_l = Wm2 + (size_t)l * DDIM * DDIM;

    k_gemm<false, false, false, false><<<gemm_grid, 256, 0, stream>>>(x, Wq_l, nullptr, nullptr, qn, NN);
    k_gemm<false, false, false, true><<<gemm_grid, 256, 0, stream>>>(x, Wk_l, nullptr, nullptr, knb, NN);
    k_gemm<false, false, false, true><<<gemm_grid, 256, 0, stream>>>(x, Wv_l, nullptr, nullptr, vnb, NN);

    k_attn<<<NN / 4, 256, 0, stream>>>(qn, knb, vnb, de, ei, rowptr, eids, We_l, msg);

    k_gemm<false, false, true, false><<<gemm_grid, 256, 0, stream>>>(msg, Wo_l, nullptr, x, x, NN);
    k_ln<<<NN, 64, 0, stream>>>(x, ln_g + (size_t)l * DDIM, ln_b + (size_t)l * DDIM, hb);
    k_gemm<true, true, false, false><<<gemm_grid, 256, 0, stream>>>(hb, Wm1_l, bm1 + (size_t)l * DDIM, nullptr, h2, NN);
    k_gemm<true, false, true, false><<<gemm_grid, 256, 0, stream>>>(h2, Wm2_l, bm2 + (size_t)l * DDIM, x, x, NN);
  }

  k_fill_f<<<(NGRAPH * DDIM + 255) / 256, 256, 0, stream>>>(gb, 0.f, NGRAPH * DDIM);
  k_graphsum<<<(NN + 511) / 512, 128, 0, stream>>>(x, batch, gb);
  k_out<<<(NGRAPH * DOUT + 255) / 256, 256, 0, stream>>>(gb, W_out, b_out, out);
}

// Round 3
// 1028.718 us; speedup vs baseline: 2.0124x; 2.0124x over previous
//
#include <hip/hip_runtime.h>
#include <math.h>

#define NN 50000
#define NE 400000
#define DDIM 128
#define NHEAD 4
#define NRAD 50
#define NGRAPH 100
#define TEMB 32
#define DOUT 512
#define CUTF 6.0f
#define PI_F 3.14159265358979323846f

typedef unsigned int uint;
typedef unsigned short ushort;
typedef __attribute__((ext_vector_type(8))) short short8;
typedef __attribute__((ext_vector_type(4))) float f32x4;

// ---------------- helpers ----------------

__device__ __forceinline__ float gelu_tanh(float v) {
  float u = 0.7978845608028654f * (v + 0.044715f * v * v * v);
  return 0.5f * v * (1.0f + tanhf(u));
}

__device__ __forceinline__ ushort f2bf(float f) {  // RNE
  uint u = __float_as_uint(f);
  uint r = (u + 0x7fffu + ((u >> 16) & 1u)) >> 16;
  return (ushort)r;
}
__device__ __forceinline__ float bfl(uint u) { return __uint_as_float(u << 16); }
__device__ __forceinline__ float bfh(uint u) { return __uint_as_float(u & 0xffff0000u); }

__global__ void k_fill_f(float* p, float v, int n) {
  int i = blockIdx.x * blockDim.x + threadIdx.x;
  if (i < n) p[i] = v;
}
__global__ void k_fill_i(int* p, int v, int n) {
  int i = blockIdx.x * blockDim.x + threadIdx.x;
  if (i < n) p[i] = v;
}

// ---------------- init: x = [emb[at], pos] @ W_init + b ----------------

__global__ void k_init(const float* __restrict__ pos, const int* __restrict__ at,
                       const float* __restrict__ emb, const float* __restrict__ W,
                       const float* __restrict__ b, float* __restrict__ x) {
  int idx = blockIdx.x * blockDim.x + threadIdx.x;
  if (idx >= NN * DDIM) return;
  int n = idx >> 7, c = idx & 127;
  const float* er = emb + (size_t)at[n] * TEMB;
  float acc = b[c];
#pragma unroll
  for (int t = 0; t < TEMB; ++t) acc = fmaf(er[t], W[t * DDIM + c], acc);
  acc = fmaf(pos[n * 3 + 0], W[(TEMB + 0) * DDIM + c], acc);
  acc = fmaf(pos[n * 3 + 1], W[(TEMB + 1) * DDIM + c], acc);
  acc = fmaf(pos[n * 3 + 2], W[(TEMB + 2) * DDIM + c], acc);
  x[idx] = acc;
}

// ---------------- per-edge distance ----------------

__global__ void k_dist(const float* __restrict__ pos, const int* __restrict__ ei,
                       float* __restrict__ de) {
  int e = blockIdx.x * blockDim.x + threadIdx.x;
  if (e >= NE) return;
  int s = ei[e], t = ei[NE + e];
  float dx = pos[s * 3 + 0] - pos[t * 3 + 0] + 1e-8f;
  float dy = pos[s * 3 + 1] - pos[t * 3 + 1] + 1e-8f;
  float dz = pos[s * 3 + 2] - pos[t * 3 + 2] + 1e-8f;
  de[e] = sqrtf(dx * dx + dy * dy + dz * dz);
}

// ---------------- CSR build ----------------

__global__ void k_hist(const int* __restrict__ ei, int* __restrict__ deg) {
  int e = blockIdx.x * blockDim.x + threadIdx.x;
  if (e >= NE) return;
  atomicAdd(&deg[ei[NE + e]], 1);
}

__global__ void k_scan(const int* __restrict__ deg, int* __restrict__ rowptr,
                       int* __restrict__ cursor) {
  __shared__ int part[1024];
  const int CHUNK = (NN + 1023) / 1024;
  int t = threadIdx.x;
  int lo = t * CHUNK, hi = lo + CHUNK;
  if (hi > NN) hi = NN;
  int s = 0;
  for (int i = lo; i < hi; ++i) s += deg[i];
  part[t] = s;
  __syncthreads();
  for (int off = 1; off < 1024; off <<= 1) {
    int v = (t >= off) ? part[t - off] : 0;
    __syncthreads();
    part[t] += v;
    __syncthreads();
  }
  int run = (t == 0) ? 0 : part[t - 1];
  for (int i = lo; i < hi; ++i) {
    rowptr[i] = run;
    cursor[i] = run;
    run += deg[i];
  }
  if (t == 1023) rowptr[NN] = part[1023];
}

__global__ void k_scatter(const int* __restrict__ ei, int* __restrict__ cursor,
                          int* __restrict__ eids) {
  int e = blockIdx.x * blockDim.x + threadIdx.x;
  if (e >= NE) return;
  int idx = atomicAdd(&cursor[ei[NE + e]], 1);
  eids[idx] = e;
}

// ---------------- MFMA GEMM: out = act(A@W + bias) (+resid), 128x128 W ----------------
// block 256 = 4 waves; 64 rows x 128 cols per block; 16x16x32 bf16 MFMA.
// LDS: A and W^T in bf16, 16B granules XOR-swizzled by (row&7).

template <bool ABF16, bool BIAS, bool GELU, bool RESID, bool OUTBF>
__global__ __launch_bounds__(256) void k_gemm(
    const void* __restrict__ Ap, const float* __restrict__ W,
    const float* __restrict__ bias, const float* __restrict__ resid,
    void* __restrict__ outp, int nrows) {
  __shared__ ushort Al[64 * 128];
  __shared__ ushort Wl[128 * 128];
  const int tid = threadIdx.x;
  const int r0 = blockIdx.x * 64;

  // stage A (64 rows x 16 granules of 8 bf16)
  if (ABF16) {
    const ushort* A = (const ushort*)Ap;
    for (int i = tid; i < 64 * 16; i += 256) {
      int r = i >> 4, g = i & 15;
      int gr = r0 + r;
      ushort4 v0 = {0, 0, 0, 0}, v1 = {0, 0, 0, 0};
      if (gr < nrows) {
        v0 = *(const ushort4*)&A[(size_t)gr * 128 + g * 8];
        v1 = *(const ushort4*)&A[(size_t)gr * 128 + g * 8 + 4];
      }
      int gs = g ^ (r & 7);
      *(ushort4*)&Al[r * 128 + gs * 8] = v0;
      *(ushort4*)&Al[r * 128 + gs * 8 + 4] = v1;
    }
  } else {
    const float* A = (const float*)Ap;
    for (int i = tid; i < 64 * 16; i += 256) {
      int r = i >> 4, g = i & 15;
      int gr = r0 + r;
      float4 f0 = {0, 0, 0, 0}, f1 = {0, 0, 0, 0};
      if (gr < nrows) {
        f0 = *(const float4*)&A[(size_t)gr * 128 + g * 8];
        f1 = *(const float4*)&A[(size_t)gr * 128 + g * 8 + 4];
      }
      int gs = g ^ (r & 7);
      ushort4 u0 = {f2bf(f0.x), f2bf(f0.y), f2bf(f0.z), f2bf(f0.w)};
      ushort4 u1 = {f2bf(f1.x), f2bf(f1.y), f2bf(f1.z), f2bf(f1.w)};
      *(ushort4*)&Al[r * 128 + gs * 8] = u0;
      *(ushort4*)&Al[r * 128 + gs * 8 + 4] = u1;
    }
  }
  // stage W transposed: Wl[col][k]
  {
    int c = tid & 127, kh = tid >> 7;
#pragma unroll
    for (int g8 = 0; g8 < 8; ++g8) {
      ushort buf[8];
#pragma unroll
      for (int u = 0; u < 8; ++u) {
        int k = kh * 64 + g8 * 8 + u;
        buf[u] = f2bf(W[k * 128 + c]);
      }
      int g = kh * 8 + g8;
      int gs = g ^ (c & 7);
      *(ushort4*)&Wl[c * 128 + gs * 8] = *(ushort4*)&buf[0];
      *(ushort4*)&Wl[c * 128 + gs * 8 + 4] = *(ushort4*)&buf[4];
    }
  }
  __syncthreads();

  const int w = tid >> 6, l = tid & 63;
  const int lg = l >> 4, lr = l & 15;
  f32x4 acc[8];
#pragma unroll
  for (int ct = 0; ct < 8; ++ct) acc[ct] = (f32x4){0.f, 0.f, 0.f, 0.f};

  const int arow = w * 16 + lr;
#pragma unroll
  for (int ks = 0; ks < 4; ++ks) {
    int ga = (ks * 4 + lg) ^ (arow & 7);
    short8 af = *(const short8*)&Al[arow * 128 + ga * 8];
#pragma unroll
    for (int ct = 0; ct < 8; ++ct) {
      int col = ct * 16 + lr;
      int gb = (ks * 4 + lg) ^ (col & 7);
      short8 bf = *(const short8*)&Wl[col * 128 + gb * 8];
      acc[ct] = __builtin_amdgcn_mfma_f32_16x16x32_bf16(af, bf, acc[ct], 0, 0, 0);
    }
  }

#pragma unroll
  for (int ct = 0; ct < 8; ++ct) {
    int col = ct * 16 + lr;
    float bv = BIAS ? bias[col] : 0.f;
#pragma unroll
    for (int r = 0; r < 4; ++r) {
      int row = r0 + w * 16 + lg * 4 + r;
      if (row >= nrows) continue;
      float v = acc[ct][r];
      if (BIAS) v += bv;
      if (GELU) v = gelu_tanh(v);
      if (RESID) v += resid[(size_t)row * 128 + col];
      if (OUTBF)
        ((ushort*)outp)[(size_t)row * 128 + col] = f2bf(v);
      else
        ((float*)outp)[(size_t)row * 128 + col] = v;
    }
  }
}

// ---------------- qe precompute: qe[n][j][h] = sum_{d in head h} We[j][d]*q[n][d] ----------------
// 8 nodes/block (4 waves x 2 reps); We staged in LDS (padded).

__global__ __launch_bounds__(256) void k_qe(const ushort* __restrict__ qnb,
                                            const float* __restrict__ We,
                                            ushort* __restrict__ qe) {
  __shared__ float Wlds[NRAD][DDIM + 1];
  __shared__ float qlds[4][DDIM];
  int tid = threadIdx.x;
  for (int i = tid; i < NRAD * DDIM; i += 256) Wlds[i / DDIM][i % DDIM] = We[i];
  __syncthreads();
  int w = tid >> 6, t = tid & 63;
  for (int rep = 0; rep < 2; ++rep) {
    int n = blockIdx.x * 8 + rep * 4 + w;
    uint qu = *(const uint*)&qnb[(size_t)n * DDIM + 2 * t];
    qlds[w][2 * t] = bfl(qu);
    qlds[w][2 * t + 1] = bfh(qu);
    if (t < NRAD) {
      float e0 = 0.f, e1 = 0.f, e2 = 0.f, e3 = 0.f;
#pragma unroll
      for (int d = 0; d < 32; ++d) e0 = fmaf(Wlds[t][d], qlds[w][d], e0);
#pragma unroll
      for (int d = 32; d < 64; ++d) e1 = fmaf(Wlds[t][d], qlds[w][d], e1);
#pragma unroll
      for (int d = 64; d < 96; ++d) e2 = fmaf(Wlds[t][d], qlds[w][d], e2);
#pragma unroll
      for (int d = 96; d < 128; ++d) e3 = fmaf(Wlds[t][d], qlds[w][d], e3);
      ushort4 o = {f2bf(e0), f2bf(e1), f2bf(e2), f2bf(e3)};
      *(ushort4*)&qe[(size_t)n * (NRAD * 4) + 4 * t] = o;
    }
  }
}

// ---------------- fused attention v2: per-node, chunk-wise flash over CSR ----------------
// wave per node; lane t owns dims 2t,2t+1 (head = t>>4). Edge metadata preloaded
// lane-parallel per 64-edge chunk; logits staged in LDS; arb (sum a*rb) per node
// turned into one 50x128 mat-vec at the end.

__device__ __forceinline__ float rbf_fill(float d, int j) {
  const float step = CUTF / (NRAD - 1);
  const float gamma = (NRAD / CUTF) * (NRAD / CUTF);
  float mu = j * step;
  float dm = d - mu;
  float env = 0.5f * (cosf(PI_F * d / CUTF) + 1.0f);
  return expf(-gamma * dm * dm) * env;
}

__global__ __launch_bounds__(256) void k_attn2(
    const ushort* __restrict__ qnb, const ushort* __restrict__ knb,
    const ushort* __restrict__ vnb, const ushort* __restrict__ qe,
    const float* __restrict__ de, const int* __restrict__ ei,
    const int* __restrict__ rowptr, const int* __restrict__ eids,
    const float* __restrict__ We, ushort* __restrict__ msgb) {
  __shared__ float llds[4][64][4];
  __shared__ float alds[4][NRAD][4];
  const int w = threadIdx.x >> 6, t = threadIdx.x & 63;
  const int n = blockIdx.x * 4 + w;
  const int h = t >> 4;
  uint qu = *(const uint*)&qnb[(size_t)n * DDIM + 2 * t];
  float q0 = bfl(qu), q1 = bfh(qu);
  float4 qe4 = {0.f, 0.f, 0.f, 0.f};
  if (t < NRAD) {
    ushort4 qv = *(const ushort4*)&qe[(size_t)n * (NRAD * 4) + 4 * t];
    qe4.x = bfl(qv.x); qe4.y = bfl(qv.y); qe4.z = bfl(qv.z); qe4.w = bfl(qv.w);
  }
  const int start = rowptr[n];
  const int deg = rowptr[n + 1] - start;

  float m = -INFINITY, s = 0.f, a0 = 0.f, a1 = 0.f;
  float4 arb = {0.f, 0.f, 0.f, 0.f};

  for (int cb = 0; cb < deg; cb += 64) {
    int cnt = min(deg - cb, 64);
    int src_t = 0;
    float d_t = 1e30f;
    if (t < cnt) {
      int eid = eids[start + cb + t];
      src_t = ei[eid];
      d_t = de[eid];
    }
    float mold = m;
    // --- loop A: logits ---
    for (int i = 0; i < cnt; ++i) {
      int src = __shfl(src_t, i);
      float dd = __shfl(d_t, i);
      uint ku = *(const uint*)&knb[(size_t)src * DDIM + 2 * t];
      float p = q0 * bfl(ku) + q1 * bfh(ku);
      p += __shfl_xor(p, 1);
      p += __shfl_xor(p, 2);
      p += __shfl_xor(p, 4);
      p += __shfl_xor(p, 8);
      float rbq = 0.f;
      if (dd < CUTF) {
        float rb = (t < NRAD) ? rbf_fill(dd, t) : 0.f;
        float cx = rb * qe4.x, cy = rb * qe4.y, cz = rb * qe4.z, cw = rb * qe4.w;
#pragma unroll
        for (int ms = 1; ms < 64; ms <<= 1) {
          cx += __shfl_xor(cx, ms);
          cy += __shfl_xor(cy, ms);
          cz += __shfl_xor(cz, ms);
          cw += __shfl_xor(cw, ms);
        }
        rbq = (h == 0) ? cx : (h == 1) ? cy : (h == 2) ? cz : cw;
      }
      float logit = (p + rbq) * 0.17677669529663687f;
      if ((t & 15) == 0) llds[w][i][h] = logit;
      m = fmaxf(m, logit);
    }
    // --- merge: rescale prior state to new max ---
    float4 m4 = {__shfl(m, 0), __shfl(m, 16), __shfl(m, 32), __shfl(m, 48)};
    float4 mo4 = {__shfl(mold, 0), __shfl(mold, 16), __shfl(mold, 32), __shfl(mold, 48)};
    float4 f4;
    f4.x = (mo4.x == -INFINITY) ? 0.f : expf(mo4.x - m4.x);
    f4.y = (mo4.y == -INFINITY) ? 0.f : expf(mo4.y - m4.y);
    f4.z = (mo4.z == -INFINITY) ? 0.f : expf(mo4.z - m4.z);
    f4.w = (mo4.w == -INFINITY) ? 0.f : expf(mo4.w - m4.w);
    float fo = (h == 0) ? f4.x : (h == 1) ? f4.y : (h == 2) ? f4.z : f4.w;
    s *= fo; a0 *= fo; a1 *= fo;
    arb.x *= f4.x; arb.y *= f4.y; arb.z *= f4.z; arb.w *= f4.w;
    // --- loop B: exp-sum + weighted accumulation (no serial dependence) ---
    for (int i = 0; i < cnt; ++i) {
      int src = __shfl(src_t, i);
      float dd = __shfl(d_t, i);
      float lo = llds[w][i][h];
      float ae = expf(lo - m);
      s += ae;
      uint vu = *(const uint*)&vnb[(size_t)src * DDIM + 2 * t];
      a0 = fmaf(ae, bfl(vu), a0);
      a1 = fmaf(ae, bfh(vu), a1);
      if (dd < CUTF) {
        float4 lo4 = *(float4*)&llds[w][i][0];
        float rb = (t < NRAD) ? rbf_fill(dd, t) : 0.f;
        arb.x = fmaf(rb, expf(lo4.x - m4.x), arb.x);
        arb.y = fmaf(rb, expf(lo4.y - m4.y), arb.y);
        arb.z = fmaf(rb, expf(lo4.z - m4.z), arb.z);
        arb.w = fmaf(rb, expf(lo4.w - m4.w), arb.w);
      }
    }
  }

  // --- finalize: normalize, arb @ We mat-vec ---
  float4 s4 = {__shfl(s, 0), __shfl(s, 16), __shfl(s, 32), __shfl(s, 48)};
  float4 inv4 = {1.f / (s4.x + 1e-9f), 1.f / (s4.y + 1e-9f),
                 1.f / (s4.z + 1e-9f), 1.f / (s4.w + 1e-9f)};
  float invo = (h == 0) ? inv4.x : (h == 1) ? inv4.y : (h == 2) ? inv4.z : inv4.w;
  if (t < NRAD) {
    alds[w][t][0] = arb.x * inv4.x;
    alds[w][t][1] = arb.y * inv4.y;
    alds[w][t][2] = arb.z * inv4.z;
    alds[w][t][3] = arb.w * inv4.w;
  }
  a0 *= invo;
  a1 *= invo;
#pragma unroll 10
  for (int j = 0; j < NRAD; ++j) {
    float ar = alds[w][j][h];
    float2 wv = *(const float2*)&We[j * DDIM + 2 * t];
    a0 = fmaf(ar, wv.x, a0);
    a1 = fmaf(ar, wv.y, a1);
  }
  uint pk = (uint)f2bf(a0) | ((uint)f2bf(a1) << 16);
  *(uint*)&msgb[(size_t)n * DDIM + 2 * t] = pk;
}

// ---------------- layernorm (per node, 1 wave) -> bf16 ----------------

__global__ void k_ln(const float* __restrict__ x, const float* __restrict__ g,
                     const float* __restrict__ b, ushort* __restrict__ h) {
  int n = blockIdx.x;
  int t = threadIdx.x;  // 64
  float v0 = x[(size_t)n * DDIM + t];
  float v1 = x[(size_t)n * DDIM + 64 + t];
  float s = v0 + v1;
  float ss = v0 * v0 + v1 * v1;
#pragma unroll
  for (int m = 32; m >= 1; m >>= 1) {
    s += __shfl_xor(s, m);
    ss += __shfl_xor(ss, m);
  }
  float mean = s * (1.0f / DDIM);
  float var = ss * (1.0f / DDIM) - mean * mean;
  float inv = rsqrtf(var + 1e-5f);
  h[(size_t)n * DDIM + t] = f2bf((v0 - mean) * inv * g[t] + b[t]);
  h[(size_t)n * DDIM + 64 + t] = f2bf((v1 - mean) * inv * g[64 + t] + b[64 + t]);
}

// ---------------- graph sum (batch is sorted) ----------------

__global__ void k_graphsum(const float* __restrict__ x, const int* __restrict__ batch,
                           float* __restrict__ g) {
  int t = threadIdx.x;  // 128 dims
  int n0 = blockIdx.x * 512;
  int nend = n0 + 512;
  if (nend > NN) nend = NN;
  if (n0 >= NN) return;
  float acc = 0.f;
  int cur = batch[n0];
  for (int n = n0; n < nend; ++n) {
    int bb = batch[n];
    if (bb != cur) {
      atomicAdd(&g[(size_t)cur * DDIM + t], acc);
      acc = 0.f;
      cur = bb;
    }
    acc += x[(size_t)n * DDIM + t];
  }
  atomicAdd(&g[(size_t)cur * DDIM + t], acc);
}

// ---------------- output projection ----------------

__global__ void k_out(const float* __restrict__ g, const float* __restrict__ W,
                      const float* __restrict__ b, float* __restrict__ out) {
  int idx = blockIdx.x * blockDim.x + threadIdx.x;
  if (idx >= NGRAPH * DOUT) return;
  int r = idx / DOUT, c = idx % DOUT;
  float acc = b[c];
#pragma unroll 8
  for (int k = 0; k < DDIM; ++k) acc = fmaf(g[r * DDIM + k], W[k * DOUT + c], acc);
  out[idx] = acc;
}

// ---------------- launch ----------------

extern "C" void kernel_launch(void* const* d_in, const int* in_sizes, int n_in,
                              void* d_out, int out_size, void* d_ws, size_t ws_size,
                              hipStream_t stream) {
  const float* pos = (const float*)d_in[0];
  const int* at = (const int*)d_in[1];
  const int* ei = (const int*)d_in[2];
  const int* batch = (const int*)d_in[3];
  const float* emb = (const float*)d_in[4];
  const float* W_init = (const float*)d_in[5];
  const float* b_init = (const float*)d_in[6];
  const float* Wq = (const float*)d_in[7];
  const float* Wk = (const float*)d_in[8];
  const float* Wv = (const float*)d_in[9];
  const float* We = (const float*)d_in[10];
  const float* Wo = (const float*)d_in[11];
  const float* Wm1 = (const float*)d_in[12];
  const float* bm1 = (const float*)d_in[13];
  const float* Wm2 = (const float*)d_in[14];
  const float* bm2 = (const float*)d_in[15];
  const float* ln_g = (const float*)d_in[16];
  const float* ln_b = (const float*)d_in[17];
  const float* W_out = (const float*)d_in[18];
  const float* b_out = (const float*)d_in[19];
  float* out = (float*)d_out;

  const size_t ND = (size_t)NN * DDIM;  // 6.4M
  float* x = (float*)d_ws;              // f32 ND
  ushort* qnb = (ushort*)(x + ND);      // bf16 ND (later: hb)
  ushort* knb = qnb + ND;               // bf16 ND (later: h2)
  ushort* vnb = knb + ND;               // bf16 ND
  ushort* msgb = vnb + ND;              // bf16 ND
  ushort* qe = msgb + ND;               // bf16 NN*200
  float* de = (float*)(qe + (size_t)NN * 200);  // f32 NE
  int* deg = (int*)(de + NE);
  int* cursor = deg + NN;
  int* rowptr = cursor + NN;
  int* eids = rowptr + NN + 64;
  float* gb = (float*)(eids + NE);
  // total ~102 MB

  ushort* hb = qnb;
  ushort* h2 = knb;

  k_init<<<(NN * DDIM + 255) / 256, 256, 0, stream>>>(pos, at, emb, W_init, b_init, x);
  k_dist<<<(NE + 255) / 256, 256, 0, stream>>>(pos, ei, de);
  k_fill_i<<<(NN + 255) / 256, 256, 0, stream>>>(deg, 0, NN);
  k_hist<<<(NE + 255) / 256, 256, 0, stream>>>(ei, deg);
  k_scan<<<1, 1024, 0, stream>>>(deg, rowptr, cursor);
  k_scatter<<<(NE + 255) / 256, 256, 0, stream>>>(ei, cursor, eids);

  const int gemm_grid = (NN + 63) / 64;
  for (int l = 0; l < 2; ++l) {
    const float* Wq_l = Wq + (size_t)l * DDIM * DDIM;
    const float* Wk_l = Wk + (size_t)l * DDIM * DDIM;
    const float* Wv_l = Wv + (size_t)l * DDIM * DDIM;
    const float* We_l = We + (size_t)l * NRAD * DDIM;
    const float* Wo_l = Wo + (size_t)l * DDIM * DDIM;
    const float* Wm1_l = Wm1 + (size_t)l * DDIM * DDIM;
    const float* Wm2_l = Wm2 + (size_t)l * DDIM * DDIM;

    k_gemm<false, false, false, false, true><<<gemm_grid, 256, 0, stream>>>(x, Wq_l, nullptr, nullptr, qnb, NN);
    k_gemm<false, false, false, false, true><<<gemm_grid, 256, 0, stream>>>(x, Wk_l, nullptr, nullptr, knb, NN);
    k_gemm<false, false, false, false, true><<<gemm_grid, 256, 0, stream>>>(x, Wv_l, nullptr, nullptr, vnb, NN);

    k_qe<<<NN / 8, 256, 0, stream>>>(qnb, We_l, qe);
    k_attn2<<<NN / 4, 256, 0, stream>>>(qnb, knb, vnb, qe, de, ei, rowptr, eids, We_l, msgb);

    k_gemm<true, false, false, true, false><<<gemm_grid, 256, 0, stream>>>(msgb, Wo_l, nullptr, x, x, NN);
    k_ln<<<NN, 64, 0, stream>>>(x, ln_g + (size_t)l * DDIM, ln_b + (size_t)l * DDIM, hb);
    k_gemm<true, true, true, false, true><<<gemm_grid, 256, 0, stream>>>(hb, Wm1_l, bm1 + (size_t)l * DDIM, nullptr, h2, NN);
    k_gemm<true, true, false, true, false><<<gemm_grid, 256, 0, stream>>>(h2, Wm2_l, bm2 + (size_t)l * DDIM, x, x, NN);
  }

  k_fill_f<<<(NGRAPH * DDIM + 255) / 256, 256, 0, stream>>>(gb, 0.f, NGRAPH * DDIM);
  k_graphsum<<<(NN + 511) / 512, 128, 0, stream>>>(x, batch, gb);
  k_out<<<(NGRAPH * DOUT + 255) / 256, 256, 0, stream>>>(gb, W_out, b_out, out);
}

// Round 4
// 838.889 us; speedup vs baseline: 2.4677x; 1.2263x over previous
//
#include <hip/hip_runtime.h>
#include <math.h>

#define NN 50000
#define NE 400000
#define DDIM 128
#define NHEAD 4
#define NRAD 50
#define NGRAPH 100
#define TEMB 32
#define DOUT 512
#define CUTF 6.0f
#define PI_F 3.14159265358979323846f

typedef unsigned int uint;
typedef unsigned short ushort;
typedef __attribute__((ext_vector_type(8))) short short8;
typedef __attribute__((ext_vector_type(4))) float f32x4;

// ---------------- helpers ----------------

__device__ __forceinline__ float gelu_tanh(float v) {
  float u = 0.7978845608028654f * (v + 0.044715f * v * v * v);
  return 0.5f * v * (1.0f + tanhf(u));
}

__device__ __forceinline__ ushort f2bf(float f) {  // RNE
  uint u = __float_as_uint(f);
  uint r = (u + 0x7fffu + ((u >> 16) & 1u)) >> 16;
  return (ushort)r;
}
__device__ __forceinline__ float bfl(uint u) { return __uint_as_float(u << 16); }
__device__ __forceinline__ float bfh(uint u) { return __uint_as_float(u & 0xffff0000u); }

__global__ void k_fill_f(float* p, float v, int n) {
  int i = blockIdx.x * blockDim.x + threadIdx.x;
  if (i < n) p[i] = v;
}
__global__ void k_fill_i(int* p, int v, int n) {
  int i = blockIdx.x * blockDim.x + threadIdx.x;
  if (i < n) p[i] = v;
}

// ---------------- weight pre-convert + transpose: Wtb[l][fam][c][k] bf16 ----------------

__global__ void k_wconv(const float* __restrict__ Wq, const float* __restrict__ Wk,
                        const float* __restrict__ Wv, const float* __restrict__ Wo,
                        const float* __restrict__ Wm1, const float* __restrict__ Wm2,
                        ushort* __restrict__ Wtb) {
  int idx = blockIdx.x * 256 + threadIdx.x;  // 12*16384
  int m = idx >> 14;
  int r = idx & 16383;
  int c = r >> 7, k = r & 127;
  int l = m / 6, fam = m % 6;
  const float* src = fam == 0 ? Wq : fam == 1 ? Wk : fam == 2 ? Wv
                   : fam == 3 ? Wo : fam == 4 ? Wm1 : Wm2;
  Wtb[idx] = f2bf(src[l * 16384 + k * 128 + c]);
}

// ---------------- init: x = [emb[at], pos] @ W_init + b ----------------

__global__ void k_init(const float* __restrict__ pos, const int* __restrict__ at,
                       const float* __restrict__ emb, const float* __restrict__ W,
                       const float* __restrict__ b, float* __restrict__ x) {
  int idx = blockIdx.x * blockDim.x + threadIdx.x;
  if (idx >= NN * DDIM) return;
  int n = idx >> 7, c = idx & 127;
  const float* er = emb + (size_t)at[n] * TEMB;
  float acc = b[c];
#pragma unroll
  for (int t = 0; t < TEMB; ++t) acc = fmaf(er[t], W[t * DDIM + c], acc);
  acc = fmaf(pos[n * 3 + 0], W[(TEMB + 0) * DDIM + c], acc);
  acc = fmaf(pos[n * 3 + 1], W[(TEMB + 1) * DDIM + c], acc);
  acc = fmaf(pos[n * 3 + 2], W[(TEMB + 2) * DDIM + c], acc);
  x[idx] = acc;
}

// ---------------- per-edge distance + degree histogram (fused) ----------------

__global__ void k_edge(const float* __restrict__ pos, const int* __restrict__ ei,
                       float* __restrict__ de, int* __restrict__ deg) {
  int e = blockIdx.x * blockDim.x + threadIdx.x;
  if (e >= NE) return;
  int s = ei[e], t = ei[NE + e];
  float dx = pos[s * 3 + 0] - pos[t * 3 + 0] + 1e-8f;
  float dy = pos[s * 3 + 1] - pos[t * 3 + 1] + 1e-8f;
  float dz = pos[s * 3 + 2] - pos[t * 3 + 2] + 1e-8f;
  de[e] = sqrtf(dx * dx + dy * dy + dz * dz);
  atomicAdd(&deg[t], 1);
}

// ---------------- CSR scan + scatter ----------------

__global__ void k_scan(const int* __restrict__ deg, int* __restrict__ rowptr,
                       int* __restrict__ cursor) {
  __shared__ int part[1024];
  const int CHUNK = (NN + 1023) / 1024;
  int t = threadIdx.x;
  int lo = t * CHUNK, hi = lo + CHUNK;
  if (hi > NN) hi = NN;
  int s = 0;
  for (int i = lo; i < hi; ++i) s += deg[i];
  part[t] = s;
  __syncthreads();
  for (int off = 1; off < 1024; off <<= 1) {
    int v = (t >= off) ? part[t - off] : 0;
    __syncthreads();
    part[t] += v;
    __syncthreads();
  }
  int run = (t == 0) ? 0 : part[t - 1];
  for (int i = lo; i < hi; ++i) {
    rowptr[i] = run;
    cursor[i] = run;
    run += deg[i];
  }
  if (t == 1023) rowptr[NN] = part[1023];
}

__global__ void k_scatter(const int* __restrict__ ei, int* __restrict__ cursor,
                          int* __restrict__ eids) {
  int e = blockIdx.x * blockDim.x + threadIdx.x;
  if (e >= NE) return;
  int idx = atomicAdd(&cursor[ei[NE + e]], 1);
  eids[idx] = e;
}

// ---------------- fused QKV GEMM: stage x once, 3 weights ----------------
// block 256 = 4 waves; 128 rows x 128 cols; 16x16x32 bf16 MFMA; wave owns 32 rows.

__global__ __launch_bounds__(256) void k_qkv(
    const float* __restrict__ x, const ushort* __restrict__ Wt3,
    ushort* __restrict__ qo, ushort* __restrict__ ko, ushort* __restrict__ vo) {
  __shared__ ushort Al[128 * 128];
  __shared__ ushort Wl[128 * 128];
  const int tid = threadIdx.x;
  const int r0 = blockIdx.x * 128;

  for (int i = tid; i < 128 * 16; i += 256) {
    int r = i >> 4, g = i & 15;
    int gr = r0 + r;
    float4 f0 = {0, 0, 0, 0}, f1 = {0, 0, 0, 0};
    if (gr < NN) {
      f0 = *(const float4*)&x[(size_t)gr * 128 + g * 8];
      f1 = *(const float4*)&x[(size_t)gr * 128 + g * 8 + 4];
    }
    int gs = g ^ (r & 7);
    ushort4 u0 = {f2bf(f0.x), f2bf(f0.y), f2bf(f0.z), f2bf(f0.w)};
    ushort4 u1 = {f2bf(f1.x), f2bf(f1.y), f2bf(f1.z), f2bf(f1.w)};
    *(ushort4*)&Al[r * 128 + gs * 8] = u0;
    *(ushort4*)&Al[r * 128 + gs * 8 + 4] = u1;
  }

  const int w = tid >> 6, l = tid & 63;
  const int lg = l >> 4, lr = l & 15;

  for (int m = 0; m < 3; ++m) {
    for (int i = tid; i < 128 * 16; i += 256) {
      int c = i >> 4, g = i & 15;
      ushort4 w0 = *(const ushort4*)&Wt3[m * 16384 + c * 128 + g * 8];
      ushort4 w1 = *(const ushort4*)&Wt3[m * 16384 + c * 128 + g * 8 + 4];
      int gs = g ^ (c & 7);
      *(ushort4*)&Wl[c * 128 + gs * 8] = w0;
      *(ushort4*)&Wl[c * 128 + gs * 8 + 4] = w1;
    }
    __syncthreads();

    f32x4 acc[2][8];
#pragma unroll
    for (int rt = 0; rt < 2; ++rt)
#pragma unroll
      for (int ct = 0; ct < 8; ++ct) acc[rt][ct] = (f32x4){0.f, 0.f, 0.f, 0.f};

#pragma unroll
    for (int ks = 0; ks < 4; ++ks) {
      short8 af[2];
#pragma unroll
      for (int rt = 0; rt < 2; ++rt) {
        int arow = w * 32 + rt * 16 + lr;
        int ga = (ks * 4 + lg) ^ (arow & 7);
        af[rt] = *(const short8*)&Al[arow * 128 + ga * 8];
      }
#pragma unroll
      for (int ct = 0; ct < 8; ++ct) {
        int col = ct * 16 + lr;
        int gb = (ks * 4 + lg) ^ (col & 7);
        short8 bf = *(const short8*)&Wl[col * 128 + gb * 8];
#pragma unroll
        for (int rt = 0; rt < 2; ++rt)
          acc[rt][ct] = __builtin_amdgcn_mfma_f32_16x16x32_bf16(af[rt], bf, acc[rt][ct], 0, 0, 0);
      }
    }

    ushort* o = (m == 0) ? qo : (m == 1) ? ko : vo;
#pragma unroll
    for (int rt = 0; rt < 2; ++rt)
#pragma unroll
      for (int ct = 0; ct < 8; ++ct) {
        int col = ct * 16 + lr;
#pragma unroll
        for (int r = 0; r < 4; ++r) {
          int row = r0 + w * 32 + rt * 16 + lg * 4 + r;
          if (row < NN) o[(size_t)row * 128 + col] = f2bf(acc[rt][ct][r]);
        }
      }
    __syncthreads();
  }
}

// ---------------- general GEMM: out = act(A@W + bias) (+resid), A bf16, Wt bf16 ----------------

template <bool BIAS, bool GELU, bool RESID>
__global__ __launch_bounds__(256) void k_gemm2(
    const ushort* __restrict__ A, const ushort* __restrict__ Wt,
    const float* __restrict__ bias, const float* __restrict__ resid,
    void* __restrict__ outp) {
  __shared__ ushort Al[128 * 128];
  __shared__ ushort Wl[128 * 128];
  const int tid = threadIdx.x;
  const int r0 = blockIdx.x * 128;

  for (int i = tid; i < 128 * 16; i += 256) {
    int r = i >> 4, g = i & 15;
    int gr = r0 + r;
    ushort4 v0 = {0, 0, 0, 0}, v1 = {0, 0, 0, 0};
    if (gr < NN) {
      v0 = *(const ushort4*)&A[(size_t)gr * 128 + g * 8];
      v1 = *(const ushort4*)&A[(size_t)gr * 128 + g * 8 + 4];
    }
    int gs = g ^ (r & 7);
    *(ushort4*)&Al[r * 128 + gs * 8] = v0;
    *(ushort4*)&Al[r * 128 + gs * 8 + 4] = v1;
  }
  for (int i = tid; i < 128 * 16; i += 256) {
    int c = i >> 4, g = i & 15;
    ushort4 w0 = *(const ushort4*)&Wt[c * 128 + g * 8];
    ushort4 w1 = *(const ushort4*)&Wt[c * 128 + g * 8 + 4];
    int gs = g ^ (c & 7);
    *(ushort4*)&Wl[c * 128 + gs * 8] = w0;
    *(ushort4*)&Wl[c * 128 + gs * 8 + 4] = w1;
  }
  __syncthreads();

  const int w = tid >> 6, l = tid & 63;
  const int lg = l >> 4, lr = l & 15;
  f32x4 acc[2][8];
#pragma unroll
  for (int rt = 0; rt < 2; ++rt)
#pragma unroll
    for (int ct = 0; ct < 8; ++ct) acc[rt][ct] = (f32x4){0.f, 0.f, 0.f, 0.f};

#pragma unroll
  for (int ks = 0; ks < 4; ++ks) {
    short8 af[2];
#pragma unroll
    for (int rt = 0; rt < 2; ++rt) {
      int arow = w * 32 + rt * 16 + lr;
      int ga = (ks * 4 + lg) ^ (arow & 7);
      af[rt] = *(const short8*)&Al[arow * 128 + ga * 8];
    }
#pragma unroll
    for (int ct = 0; ct < 8; ++ct) {
      int col = ct * 16 + lr;
      int gb = (ks * 4 + lg) ^ (col & 7);
      short8 bf = *(const short8*)&Wl[col * 128 + gb * 8];
#pragma unroll
      for (int rt = 0; rt < 2; ++rt)
        acc[rt][ct] = __builtin_amdgcn_mfma_f32_16x16x32_bf16(af[rt], bf, acc[rt][ct], 0, 0, 0);
    }
  }

#pragma unroll
  for (int rt = 0; rt < 2; ++rt)
#pragma unroll
    for (int ct = 0; ct < 8; ++ct) {
      int col = ct * 16 + lr;
      float bv = BIAS ? bias[col] : 0.f;
#pragma unroll
      for (int r = 0; r < 4; ++r) {
        int row = r0 + w * 32 + rt * 16 + lg * 4 + r;
        if (row >= NN) continue;
        float v = acc[rt][ct][r];
        if (BIAS) v += bv;
        if (GELU) v = gelu_tanh(v);
        if (RESID) {
          v += resid[(size_t)row * 128 + col];
          ((float*)outp)[(size_t)row * 128 + col] = v;
        } else {
          ((ushort*)outp)[(size_t)row * 128 + col] = f2bf(v);
        }
      }
    }
}

// ---------------- qe precompute: qe[n][j][h] ----------------

__global__ __launch_bounds__(256) void k_qe(const ushort* __restrict__ qnb,
                                            const float* __restrict__ We,
                                            ushort* __restrict__ qe) {
  __shared__ float Wlds[NRAD][DDIM + 1];
  __shared__ float qlds[4][DDIM];
  int tid = threadIdx.x;
  for (int i = tid; i < NRAD * DDIM; i += 256) Wlds[i / DDIM][i % DDIM] = We[i];
  __syncthreads();
  int w = tid >> 6, t = tid & 63;
  for (int rep = 0; rep < 2; ++rep) {
    int n = blockIdx.x * 8 + rep * 4 + w;
    uint qu = *(const uint*)&qnb[(size_t)n * DDIM + 2 * t];
    qlds[w][2 * t] = bfl(qu);
    qlds[w][2 * t + 1] = bfh(qu);
    if (t < NRAD) {
      float e0 = 0.f, e1 = 0.f, e2 = 0.f, e3 = 0.f;
#pragma unroll
      for (int d = 0; d < 32; ++d) e0 = fmaf(Wlds[t][d], qlds[w][d], e0);
#pragma unroll
      for (int d = 32; d < 64; ++d) e1 = fmaf(Wlds[t][d], qlds[w][d], e1);
#pragma unroll
      for (int d = 64; d < 96; ++d) e2 = fmaf(Wlds[t][d], qlds[w][d], e2);
#pragma unroll
      for (int d = 96; d < 128; ++d) e3 = fmaf(Wlds[t][d], qlds[w][d], e3);
      ushort4 o = {f2bf(e0), f2bf(e1), f2bf(e2), f2bf(e3)};
      *(ushort4*)&qe[(size_t)n * (NRAD * 4) + 4 * t] = o;
    }
  }
}

// ---------------- fused attention v3: single-pass (no running max), per-node wave ----------------
// Softmax is shift-invariant: exp(logit) directly, capped at 60 as overflow insurance.
// lane t owns dims 2t,2t+1 (head h=t>>4) and radial index j=t.

__device__ __forceinline__ float rbf_fill(float d, int j) {
  const float step = CUTF / (NRAD - 1);
  const float gamma = (NRAD / CUTF) * (NRAD / CUTF);
  float mu = j * step;
  float dm = d - mu;
  float env = 0.5f * (__cosf(PI_F * d / CUTF) + 1.0f);
  return __expf(-gamma * dm * dm) * env;
}

__global__ __launch_bounds__(256) void k_attn3(
    const ushort* __restrict__ qnb, const ushort* __restrict__ knb,
    const ushort* __restrict__ vnb, const ushort* __restrict__ qe,
    const float* __restrict__ de, const int* __restrict__ ei,
    const int* __restrict__ rowptr, const int* __restrict__ eids,
    const float* __restrict__ We, ushort* __restrict__ msgb) {
  __shared__ float qel[4][64][4];   // [wave][j(padded)][head]; reused for arbn in epilogue
  __shared__ float rbl[4][64];
  __shared__ float ael[4][4];
  __shared__ ushort Wel[NRAD * DDIM];
  const int tid = threadIdx.x;
  for (int i = tid; i < NRAD * DDIM; i += 256) Wel[i] = f2bf(We[i]);
  __syncthreads();

  const int w = tid >> 6, t = tid & 63;
  const int n = blockIdx.x * 4 + w;
  const int h = t >> 4;
  uint qu = *(const uint*)&qnb[(size_t)n * DDIM + 2 * t];
  const float q0 = bfl(qu), q1 = bfh(qu);
  if (t < NRAD) {
    ushort4 qv = *(const ushort4*)&qe[(size_t)n * (NRAD * 4) + 4 * t];
    qel[w][t][0] = bfl(qv.x);
    qel[w][t][1] = bfl(qv.y);
    qel[w][t][2] = bfl(qv.z);
    qel[w][t][3] = bfl(qv.w);
  } else {
    qel[w][t][0] = 0.f; qel[w][t][1] = 0.f; qel[w][t][2] = 0.f; qel[w][t][3] = 0.f;
  }
  const int start = rowptr[n];
  const int deg = rowptr[n + 1] - start;

  float s = 0.f, a0 = 0.f, a1 = 0.f;
  float4 arb = {0.f, 0.f, 0.f, 0.f};
  const int j0 = t & 15;

  for (int cb = 0; cb < deg; cb += 64) {
    int cnt = min(deg - cb, 64);
    int src_t = 0;
    float d_t = 1e30f;
    if (t < cnt) {
      int eid = eids[start + cb + t];
      src_t = ei[eid];
      d_t = de[eid];
    }
    for (int i = 0; i < cnt; ++i) {
      int src = __shfl(src_t, i);
      float dd = __shfl(d_t, i);
      uint ku = *(const uint*)&knb[(size_t)src * DDIM + 2 * t];
      uint vu = *(const uint*)&vnb[(size_t)src * DDIM + 2 * t];
      float pr = q0 * bfl(ku) + q1 * bfh(ku);
      bool nr = dd < CUTF;  // wave-uniform
      float rb = 0.f;
      if (nr) {
        rb = (t < NRAD) ? rbf_fill(dd, t) : 0.f;
        rbl[w][t] = rb;
        pr = fmaf(rbl[w][j0], qel[w][j0][h], pr);
        pr = fmaf(rbl[w][j0 + 16], qel[w][j0 + 16][h], pr);
        pr = fmaf(rbl[w][j0 + 32], qel[w][j0 + 32][h], pr);
        pr = fmaf(rbl[w][j0 + 48], qel[w][j0 + 48][h], pr);
      }
      pr += __shfl_xor(pr, 1);
      pr += __shfl_xor(pr, 2);
      pr += __shfl_xor(pr, 4);
      pr += __shfl_xor(pr, 8);
      if ((t & 15) == 0)
        ael[w][h] = __expf(fminf(pr * 0.17677669529663687f, 60.f));
      float4 ae4 = *(float4*)&ael[w][0];
      float ae = (h == 0) ? ae4.x : (h == 1) ? ae4.y : (h == 2) ? ae4.z : ae4.w;
      s += ae;
      a0 = fmaf(ae, bfl(vu), a0);
      a1 = fmaf(ae, bfh(vu), a1);
      if (nr) {
        arb.x = fmaf(rb, ae4.x, arb.x);
        arb.y = fmaf(rb, ae4.y, arb.y);
        arb.z = fmaf(rb, ae4.z, arb.z);
        arb.w = fmaf(rb, ae4.w, arb.w);
      }
    }
  }

  // finalize: normalize; msg = a_norm + (arb_norm @ We)
  float4 s4 = {__shfl(s, 0), __shfl(s, 16), __shfl(s, 32), __shfl(s, 48)};
  float4 inv4 = {1.f / (s4.x + 1e-9f), 1.f / (s4.y + 1e-9f),
                 1.f / (s4.z + 1e-9f), 1.f / (s4.w + 1e-9f)};
  float invo = (h == 0) ? inv4.x : (h == 1) ? inv4.y : (h == 2) ? inv4.z : inv4.w;
  if (t < NRAD) {
    qel[w][t][0] = arb.x * inv4.x;
    qel[w][t][1] = arb.y * inv4.y;
    qel[w][t][2] = arb.z * inv4.z;
    qel[w][t][3] = arb.w * inv4.w;
  }
  a0 *= invo;
  a1 *= invo;
#pragma unroll 10
  for (int j = 0; j < NRAD; ++j) {
    float ar = qel[w][j][h];
    uint wu = *(const uint*)&Wel[j * DDIM + 2 * t];
    a0 = fmaf(ar, bfl(wu), a0);
    a1 = fmaf(ar, bfh(wu), a1);
  }
  uint pk = (uint)f2bf(a0) | ((uint)f2bf(a1) << 16);
  *(uint*)&msgb[(size_t)n * DDIM + 2 * t] = pk;
}

// ---------------- layernorm (per node, 1 wave) -> bf16 ----------------

__global__ void k_ln(const float* __restrict__ x, const float* __restrict__ g,
                     const float* __restrict__ b, ushort* __restrict__ h) {
  int n = blockIdx.x;
  int t = threadIdx.x;  // 64
  float v0 = x[(size_t)n * DDIM + t];
  float v1 = x[(size_t)n * DDIM + 64 + t];
  float s = v0 + v1;
  float ss = v0 * v0 + v1 * v1;
#pragma unroll
  for (int m = 32; m >= 1; m >>= 1) {
    s += __shfl_xor(s, m);
    ss += __shfl_xor(ss, m);
  }
  float mean = s * (1.0f / DDIM);
  float var = ss * (1.0f / DDIM) - mean * mean;
  float inv = rsqrtf(var + 1e-5f);
  h[(size_t)n * DDIM + t] = f2bf((v0 - mean) * inv * g[t] + b[t]);
  h[(size_t)n * DDIM + 64 + t] = f2bf((v1 - mean) * inv * g[64 + t] + b[64 + t]);
}

// ---------------- graph sum (batch is sorted) ----------------

__global__ void k_graphsum(const float* __restrict__ x, const int* __restrict__ batch,
                           float* __restrict__ g) {
  int t = threadIdx.x;  // 128 dims
  int n0 = blockIdx.x * 512;
  int nend = n0 + 512;
  if (nend > NN) nend = NN;
  if (n0 >= NN) return;
  float acc = 0.f;
  int cur = batch[n0];
  for (int n = n0; n < nend; ++n) {
    int bb = batch[n];
    if (bb != cur) {
      atomicAdd(&g[(size_t)cur * DDIM + t], acc);
      acc = 0.f;
      cur = bb;
    }
    acc += x[(size_t)n * DDIM + t];
  }
  atomicAdd(&g[(size_t)cur * DDIM + t], acc);
}

// ---------------- output projection ----------------

__global__ void k_out(const float* __restrict__ g, const float* __restrict__ W,
                      const float* __restrict__ b, float* __restrict__ out) {
  int idx = blockIdx.x * blockDim.x + threadIdx.x;
  if (idx >= NGRAPH * DOUT) return;
  int r = idx / DOUT, c = idx % DOUT;
  float acc = b[c];
#pragma unroll 8
  for (int k = 0; k < DDIM; ++k) acc = fmaf(g[r * DDIM + k], W[k * DOUT + c], acc);
  out[idx] = acc;
}

// ---------------- launch ----------------

extern "C" void kernel_launch(void* const* d_in, const int* in_sizes, int n_in,
                              void* d_out, int out_size, void* d_ws, size_t ws_size,
                              hipStream_t stream) {
  const float* pos = (const float*)d_in[0];
  const int* at = (const int*)d_in[1];
  const int* ei = (const int*)d_in[2];
  const int* batch = (const int*)d_in[3];
  const float* emb = (const float*)d_in[4];
  const float* W_init = (const float*)d_in[5];
  const float* b_init = (const float*)d_in[6];
  const float* Wq = (const float*)d_in[7];
  const float* Wk = (const float*)d_in[8];
  const float* Wv = (const float*)d_in[9];
  const float* We = (const float*)d_in[10];
  const float* Wo = (const float*)d_in[11];
  const float* Wm1 = (const float*)d_in[12];
  const float* bm1 = (const float*)d_in[13];
  const float* Wm2 = (const float*)d_in[14];
  const float* bm2 = (const float*)d_in[15];
  const float* ln_g = (const float*)d_in[16];
  const float* ln_b = (const float*)d_in[17];
  const float* W_out = (const float*)d_in[18];
  const float* b_out = (const float*)d_in[19];
  float* out = (float*)d_out;

  const size_t ND = (size_t)NN * DDIM;  // 6.4M
  float* x = (float*)d_ws;              // f32 ND
  ushort* qnb = (ushort*)(x + ND);      // bf16 ND (alias hb)
  ushort* knb = qnb + ND;               // bf16 ND (alias h2)
  ushort* vnb = knb + ND;               // bf16 ND
  ushort* msgb = vnb + ND;              // bf16 ND
  ushort* qe = msgb + ND;               // bf16 NN*200
  ushort* Wtb = qe + (size_t)NN * 200;  // bf16 12*16384
  float* de = (float*)(Wtb + 12 * 16384);  // f32 NE
  int* deg = (int*)(de + NE);
  int* cursor = deg + NN;
  int* rowptr = cursor + NN;
  int* eids = rowptr + NN + 64;
  float* gb = (float*)(eids + NE);
  // total ~94 MB

  ushort* hb = qnb;
  ushort* h2 = knb;

  k_wconv<<<12 * 16384 / 256, 256, 0, stream>>>(Wq, Wk, Wv, Wo, Wm1, Wm2, Wtb);
  k_fill_i<<<(NN + 255) / 256, 256, 0, stream>>>(deg, 0, NN);
  k_init<<<(NN * DDIM + 255) / 256, 256, 0, stream>>>(pos, at, emb, W_init, b_init, x);
  k_edge<<<(NE + 255) / 256, 256, 0, stream>>>(pos, ei, de, deg);
  k_scan<<<1, 1024, 0, stream>>>(deg, rowptr, cursor);
  k_scatter<<<(NE + 255) / 256, 256, 0, stream>>>(ei, cursor, eids);

  const int gg = (NN + 127) / 128;  // 391
  for (int l = 0; l < 2; ++l) {
    const ushort* Wt_l = Wtb + (size_t)l * 6 * 16384;
    const float* We_l = We + (size_t)l * NRAD * DDIM;

    k_qkv<<<gg, 256, 0, stream>>>(x, Wt_l, qnb, knb, vnb);
    k_qe<<<NN / 8, 256, 0, stream>>>(qnb, We_l, qe);
    k_attn3<<<NN / 4, 256, 0, stream>>>(qnb, knb, vnb, qe, de, ei, rowptr, eids, We_l, msgb);

    k_gemm2<false, false, true><<<gg, 256, 0, stream>>>(msgb, Wt_l + 3 * 16384, nullptr, x, x);
    k_ln<<<NN, 64, 0, stream>>>(x, ln_g + (size_t)l * DDIM, ln_b + (size_t)l * DDIM, hb);
    k_gemm2<true, true, false><<<gg, 256, 0, stream>>>(hb, Wt_l + 4 * 16384, bm1 + (size_t)l * DDIM, nullptr, h2);
    k_gemm2<true, false, true><<<gg, 256, 0, stream>>>(h2, Wt_l + 5 * 16384, bm2 + (size_t)l * DDIM, x, x);
  }

  k_fill_f<<<(NGRAPH * DDIM + 255) / 256, 256, 0, stream>>>(gb, 0.f, NGRAPH * DDIM);
  k_graphsum<<<(NN + 511) / 512, 128, 0, stream>>>(x, batch, gb);
  k_out<<<(NGRAPH * DOUT + 255) / 256, 256, 0, stream>>>(gb, W_out, b_out, out);
}

// Round 5
// 651.673 us; speedup vs baseline: 3.1767x; 1.2873x over previous
//
#include <hip/hip_runtime.h>
#include <math.h>

#define NN 50000
#define NE 400000
#define DDIM 128
#define NHEAD 4
#define NRAD 50
#define NGRAPH 100
#define TEMB 32
#define DOUT 512
#define CUTF 6.0f
#define PI_F 3.14159265358979323846f

typedef unsigned int uint;
typedef unsigned short ushort;
typedef __attribute__((ext_vector_type(8))) short short8;
typedef __attribute__((ext_vector_type(4))) float f32x4;

// ---------------- helpers ----------------

__device__ __forceinline__ float gelu_tanh(float v) {
  float u = 0.7978845608028654f * (v + 0.044715f * v * v * v);
  return 0.5f * v * (1.0f + tanhf(u));
}

__device__ __forceinline__ ushort f2bf(float f) {  // RNE
  uint u = __float_as_uint(f);
  uint r = (u + 0x7fffu + ((u >> 16) & 1u)) >> 16;
  return (ushort)r;
}
__device__ __forceinline__ float bfl(uint u) { return __uint_as_float(u << 16); }
__device__ __forceinline__ float bfh(uint u) { return __uint_as_float(u & 0xffff0000u); }

__global__ void k_fill_f(float* p, float v, int n) {
  int i = blockIdx.x * blockDim.x + threadIdx.x;
  if (i < n) p[i] = v;
}
__global__ void k_fill_i(int* p, int v, int n) {
  int i = blockIdx.x * blockDim.x + threadIdx.x;
  if (i < n) p[i] = v;
}

// ---------------- weight pre-convert + transpose: Wtb[l][fam][c][k] bf16 ----------------

__global__ void k_wconv(const float* __restrict__ Wq, const float* __restrict__ Wk,
                        const float* __restrict__ Wv, const float* __restrict__ Wo,
                        const float* __restrict__ Wm1, const float* __restrict__ Wm2,
                        ushort* __restrict__ Wtb) {
  int idx = blockIdx.x * 256 + threadIdx.x;  // 12*16384
  int m = idx >> 14;
  int r = idx & 16383;
  int c = r >> 7, k = r & 127;
  int l = m / 6, fam = m % 6;
  const float* src = fam == 0 ? Wq : fam == 1 ? Wk : fam == 2 ? Wv
                   : fam == 3 ? Wo : fam == 4 ? Wm1 : Wm2;
  Wtb[idx] = f2bf(src[l * 16384 + k * 128 + c]);
}

// ---------------- init: x = [emb[at], pos] @ W_init + b ----------------

__global__ void k_init(const float* __restrict__ pos, const int* __restrict__ at,
                       const float* __restrict__ emb, const float* __restrict__ W,
                       const float* __restrict__ b, float* __restrict__ x) {
  int idx = blockIdx.x * blockDim.x + threadIdx.x;
  if (idx >= NN * DDIM) return;
  int n = idx >> 7, c = idx & 127;
  const float* er = emb + (size_t)at[n] * TEMB;
  float acc = b[c];
#pragma unroll
  for (int t = 0; t < TEMB; ++t) acc = fmaf(er[t], W[t * DDIM + c], acc);
  acc = fmaf(pos[n * 3 + 0], W[(TEMB + 0) * DDIM + c], acc);
  acc = fmaf(pos[n * 3 + 1], W[(TEMB + 1) * DDIM + c], acc);
  acc = fmaf(pos[n * 3 + 2], W[(TEMB + 2) * DDIM + c], acc);
  x[idx] = acc;
}

// ---------------- per-edge distance + degree histogram (fused) ----------------

__global__ void k_edge(const float* __restrict__ pos, const int* __restrict__ ei,
                       float* __restrict__ de, int* __restrict__ deg) {
  int e = blockIdx.x * blockDim.x + threadIdx.x;
  if (e >= NE) return;
  int s = ei[e], t = ei[NE + e];
  float dx = pos[s * 3 + 0] - pos[t * 3 + 0] + 1e-8f;
  float dy = pos[s * 3 + 1] - pos[t * 3 + 1] + 1e-8f;
  float dz = pos[s * 3 + 2] - pos[t * 3 + 2] + 1e-8f;
  de[e] = sqrtf(dx * dx + dy * dy + dz * dz);
  atomicAdd(&deg[t], 1);
}

// ---------------- CSR scan + scatter ----------------

__global__ void k_scan(const int* __restrict__ deg, int* __restrict__ rowptr,
                       int* __restrict__ cursor) {
  __shared__ int part[1024];
  const int CHUNK = (NN + 1023) / 1024;
  int t = threadIdx.x;
  int lo = t * CHUNK, hi = lo + CHUNK;
  if (hi > NN) hi = NN;
  int s = 0;
  for (int i = lo; i < hi; ++i) s += deg[i];
  part[t] = s;
  __syncthreads();
  for (int off = 1; off < 1024; off <<= 1) {
    int v = (t >= off) ? part[t - off] : 0;
    __syncthreads();
    part[t] += v;
    __syncthreads();
  }
  int run = (t == 0) ? 0 : part[t - 1];
  for (int i = lo; i < hi; ++i) {
    rowptr[i] = run;
    cursor[i] = run;
    run += deg[i];
  }
  if (t == 1023) rowptr[NN] = part[1023];
}

__global__ void k_scatter(const int* __restrict__ ei, int* __restrict__ cursor,
                          int* __restrict__ eids) {
  int e = blockIdx.x * blockDim.x + threadIdx.x;
  if (e >= NE) return;
  int idx = atomicAdd(&cursor[ei[NE + e]], 1);
  eids[idx] = e;
}

// ---------------- fused QKV GEMM: stage x once, 3 weights ----------------
// block 256 = 4 waves; 128 rows x 128 cols; 16x16x32 bf16 MFMA; wave owns 32 rows.

__global__ __launch_bounds__(256) void k_qkv(
    const float* __restrict__ x, const ushort* __restrict__ Wt3,
    ushort* __restrict__ qo, ushort* __restrict__ ko, ushort* __restrict__ vo) {
  __shared__ ushort Al[128 * 128];
  __shared__ ushort Wl[128 * 128];
  const int tid = threadIdx.x;
  const int r0 = blockIdx.x * 128;

  for (int i = tid; i < 128 * 16; i += 256) {
    int r = i >> 4, g = i & 15;
    int gr = r0 + r;
    float4 f0 = {0, 0, 0, 0}, f1 = {0, 0, 0, 0};
    if (gr < NN) {
      f0 = *(const float4*)&x[(size_t)gr * 128 + g * 8];
      f1 = *(const float4*)&x[(size_t)gr * 128 + g * 8 + 4];
    }
    int gs = g ^ (r & 7);
    ushort4 u0 = {f2bf(f0.x), f2bf(f0.y), f2bf(f0.z), f2bf(f0.w)};
    ushort4 u1 = {f2bf(f1.x), f2bf(f1.y), f2bf(f1.z), f2bf(f1.w)};
    *(ushort4*)&Al[r * 128 + gs * 8] = u0;
    *(ushort4*)&Al[r * 128 + gs * 8 + 4] = u1;
  }

  const int w = tid >> 6, l = tid & 63;
  const int lg = l >> 4, lr = l & 15;

  for (int m = 0; m < 3; ++m) {
    for (int i = tid; i < 128 * 16; i += 256) {
      int c = i >> 4, g = i & 15;
      ushort4 w0 = *(const ushort4*)&Wt3[m * 16384 + c * 128 + g * 8];
      ushort4 w1 = *(const ushort4*)&Wt3[m * 16384 + c * 128 + g * 8 + 4];
      int gs = g ^ (c & 7);
      *(ushort4*)&Wl[c * 128 + gs * 8] = w0;
      *(ushort4*)&Wl[c * 128 + gs * 8 + 4] = w1;
    }
    __syncthreads();

    f32x4 acc[2][8];
#pragma unroll
    for (int rt = 0; rt < 2; ++rt)
#pragma unroll
      for (int ct = 0; ct < 8; ++ct) acc[rt][ct] = (f32x4){0.f, 0.f, 0.f, 0.f};

#pragma unroll
    for (int ks = 0; ks < 4; ++ks) {
      short8 af[2];
#pragma unroll
      for (int rt = 0; rt < 2; ++rt) {
        int arow = w * 32 + rt * 16 + lr;
        int ga = (ks * 4 + lg) ^ (arow & 7);
        af[rt] = *(const short8*)&Al[arow * 128 + ga * 8];
      }
#pragma unroll
      for (int ct = 0; ct < 8; ++ct) {
        int col = ct * 16 + lr;
        int gb = (ks * 4 + lg) ^ (col & 7);
        short8 bf = *(const short8*)&Wl[col * 128 + gb * 8];
#pragma unroll
        for (int rt = 0; rt < 2; ++rt)
          acc[rt][ct] = __builtin_amdgcn_mfma_f32_16x16x32_bf16(af[rt], bf, acc[rt][ct], 0, 0, 0);
      }
    }

    ushort* o = (m == 0) ? qo : (m == 1) ? ko : vo;
#pragma unroll
    for (int rt = 0; rt < 2; ++rt)
#pragma unroll
      for (int ct = 0; ct < 8; ++ct) {
        int col = ct * 16 + lr;
#pragma unroll
        for (int r = 0; r < 4; ++r) {
          int row = r0 + w * 32 + rt * 16 + lg * 4 + r;
          if (row < NN) o[(size_t)row * 128 + col] = f2bf(acc[rt][ct][r]);
        }
      }
    __syncthreads();
  }
}

// ---------------- general GEMM: out = act(A@W + bias) (+resid) (+fused LN), A bf16 ----------------
// LNF: also emit layernorm(out) as bf16 to lnout. A row's 128 cols live in the
// 16 lanes sharing lg (8 cols each) -> 4x shfl_xor reduce for mean/var.

template <bool BIAS, bool GELU, bool RESID, bool LNF>
__global__ __launch_bounds__(256) void k_gemm2(
    const ushort* __restrict__ A, const ushort* __restrict__ Wt,
    const float* __restrict__ bias, const float* __restrict__ resid,
    void* __restrict__ outp, const float* __restrict__ lng,
    const float* __restrict__ lnb, ushort* __restrict__ lnout) {
  __shared__ ushort Al[128 * 128];
  __shared__ ushort Wl[128 * 128];
  const int tid = threadIdx.x;
  const int r0 = blockIdx.x * 128;

  for (int i = tid; i < 128 * 16; i += 256) {
    int r = i >> 4, g = i & 15;
    int gr = r0 + r;
    ushort4 v0 = {0, 0, 0, 0}, v1 = {0, 0, 0, 0};
    if (gr < NN) {
      v0 = *(const ushort4*)&A[(size_t)gr * 128 + g * 8];
      v1 = *(const ushort4*)&A[(size_t)gr * 128 + g * 8 + 4];
    }
    int gs = g ^ (r & 7);
    *(ushort4*)&Al[r * 128 + gs * 8] = v0;
    *(ushort4*)&Al[r * 128 + gs * 8 + 4] = v1;
  }
  for (int i = tid; i < 128 * 16; i += 256) {
    int c = i >> 4, g = i & 15;
    ushort4 w0 = *(const ushort4*)&Wt[c * 128 + g * 8];
    ushort4 w1 = *(const ushort4*)&Wt[c * 128 + g * 8 + 4];
    int gs = g ^ (c & 7);
    *(ushort4*)&Wl[c * 128 + gs * 8] = w0;
    *(ushort4*)&Wl[c * 128 + gs * 8 + 4] = w1;
  }
  __syncthreads();

  const int w = tid >> 6, l = tid & 63;
  const int lg = l >> 4, lr = l & 15;
  f32x4 acc[2][8];
#pragma unroll
  for (int rt = 0; rt < 2; ++rt)
#pragma unroll
    for (int ct = 0; ct < 8; ++ct) acc[rt][ct] = (f32x4){0.f, 0.f, 0.f, 0.f};

#pragma unroll
  for (int ks = 0; ks < 4; ++ks) {
    short8 af[2];
#pragma unroll
    for (int rt = 0; rt < 2; ++rt) {
      int arow = w * 32 + rt * 16 + lr;
      int ga = (ks * 4 + lg) ^ (arow & 7);
      af[rt] = *(const short8*)&Al[arow * 128 + ga * 8];
    }
#pragma unroll
    for (int ct = 0; ct < 8; ++ct) {
      int col = ct * 16 + lr;
      int gb = (ks * 4 + lg) ^ (col & 7);
      short8 bf = *(const short8*)&Wl[col * 128 + gb * 8];
#pragma unroll
      for (int rt = 0; rt < 2; ++rt)
        acc[rt][ct] = __builtin_amdgcn_mfma_f32_16x16x32_bf16(af[rt], bf, acc[rt][ct], 0, 0, 0);
    }
  }

#pragma unroll
  for (int rt = 0; rt < 2; ++rt)
#pragma unroll
    for (int r = 0; r < 4; ++r) {
      int row = r0 + w * 32 + rt * 16 + lg * 4 + r;
      bool ok = row < NN;  // uniform across the 16-lane lr group
      float v[8];
#pragma unroll
      for (int ct = 0; ct < 8; ++ct) {
        int col = ct * 16 + lr;
        float vv = acc[rt][ct][r];
        if (BIAS) vv += bias[col];
        if (GELU) vv = gelu_tanh(vv);
        if (RESID) vv += ok ? resid[(size_t)row * 128 + col] : 0.f;
        v[ct] = vv;
      }
      if (RESID || LNF) {
        if (ok)
#pragma unroll
          for (int ct = 0; ct < 8; ++ct)
            ((float*)outp)[(size_t)row * 128 + ct * 16 + lr] = v[ct];
      } else {
        if (ok)
#pragma unroll
          for (int ct = 0; ct < 8; ++ct)
            ((ushort*)outp)[(size_t)row * 128 + ct * 16 + lr] = f2bf(v[ct]);
      }
      if (LNF) {
        float s = 0.f, ss = 0.f;
#pragma unroll
        for (int ct = 0; ct < 8; ++ct) {
          s += v[ct];
          ss = fmaf(v[ct], v[ct], ss);
        }
#pragma unroll
        for (int msk = 8; msk >= 1; msk >>= 1) {
          s += __shfl_xor(s, msk);
          ss += __shfl_xor(ss, msk);
        }
        float mean = s * (1.0f / DDIM);
        float var = ss * (1.0f / DDIM) - mean * mean;
        float inv = rsqrtf(var + 1e-5f);
        if (ok)
#pragma unroll
          for (int ct = 0; ct < 8; ++ct) {
            int col = ct * 16 + lr;
            lnout[(size_t)row * 128 + col] =
                f2bf((v[ct] - mean) * inv * lng[col] + lnb[col]);
          }
      }
    }
}

// ---------------- qe precompute: qe[n][j][h] ----------------

__global__ __launch_bounds__(256) void k_qe(const ushort* __restrict__ qnb,
                                            const float* __restrict__ We,
                                            ushort* __restrict__ qe) {
  __shared__ float Wlds[NRAD][DDIM + 1];
  __shared__ float qlds[4][DDIM];
  int tid = threadIdx.x;
  for (int i = tid; i < NRAD * DDIM; i += 256) Wlds[i / DDIM][i % DDIM] = We[i];
  __syncthreads();
  int w = tid >> 6, t = tid & 63;
  for (int rep = 0; rep < 2; ++rep) {
    int n = blockIdx.x * 8 + rep * 4 + w;
    uint qu = *(const uint*)&qnb[(size_t)n * DDIM + 2 * t];
    qlds[w][2 * t] = bfl(qu);
    qlds[w][2 * t + 1] = bfh(qu);
    if (t < NRAD) {
      float e0 = 0.f, e1 = 0.f, e2 = 0.f, e3 = 0.f;
#pragma unroll
      for (int d = 0; d < 32; ++d) e0 = fmaf(Wlds[t][d], qlds[w][d], e0);
#pragma unroll
      for (int d = 32; d < 64; ++d) e1 = fmaf(Wlds[t][d], qlds[w][d], e1);
#pragma unroll
      for (int d = 64; d < 96; ++d) e2 = fmaf(Wlds[t][d], qlds[w][d], e2);
#pragma unroll
      for (int d = 96; d < 128; ++d) e3 = fmaf(Wlds[t][d], qlds[w][d], e3);
      ushort4 o = {f2bf(e0), f2bf(e1), f2bf(e2), f2bf(e3)};
      *(ushort4*)&qe[(size_t)n * (NRAD * 4) + 4 * t] = o;
    }
  }
}

// ---------------- fused attention v3: single-pass (no running max), per-node wave ----------------

__device__ __forceinline__ float rbf_fill(float d, int j) {
  const float step = CUTF / (NRAD - 1);
  const float gamma = (NRAD / CUTF) * (NRAD / CUTF);
  float mu = j * step;
  float dm = d - mu;
  float env = 0.5f * (__cosf(PI_F * d / CUTF) + 1.0f);
  return __expf(-gamma * dm * dm) * env;
}

__global__ __launch_bounds__(256) void k_attn3(
    const ushort* __restrict__ qnb, const ushort* __restrict__ knb,
    const ushort* __restrict__ vnb, const ushort* __restrict__ qe,
    const float* __restrict__ de, const int* __restrict__ ei,
    const int* __restrict__ rowptr, const int* __restrict__ eids,
    const float* __restrict__ We, ushort* __restrict__ msgb) {
  __shared__ float qel[4][64][4];   // [wave][j(padded)][head]; reused for arbn in epilogue
  __shared__ float rbl[4][64];
  __shared__ float ael[4][4];
  __shared__ ushort Wel[NRAD * DDIM];
  const int tid = threadIdx.x;
  for (int i = tid; i < NRAD * DDIM; i += 256) Wel[i] = f2bf(We[i]);
  __syncthreads();

  const int w = tid >> 6, t = tid & 63;
  const int n = blockIdx.x * 4 + w;
  const int h = t >> 4;
  uint qu = *(const uint*)&qnb[(size_t)n * DDIM + 2 * t];
  const float q0 = bfl(qu), q1 = bfh(qu);
  if (t < NRAD) {
    ushort4 qv = *(const ushort4*)&qe[(size_t)n * (NRAD * 4) + 4 * t];
    qel[w][t][0] = bfl(qv.x);
    qel[w][t][1] = bfl(qv.y);
    qel[w][t][2] = bfl(qv.z);
    qel[w][t][3] = bfl(qv.w);
  } else {
    qel[w][t][0] = 0.f; qel[w][t][1] = 0.f; qel[w][t][2] = 0.f; qel[w][t][3] = 0.f;
  }
  const int start = rowptr[n];
  const int deg = rowptr[n + 1] - start;

  float s = 0.f, a0 = 0.f, a1 = 0.f;
  float4 arb = {0.f, 0.f, 0.f, 0.f};
  const int j0 = t & 15;

  for (int cb = 0; cb < deg; cb += 64) {
    int cnt = min(deg - cb, 64);
    int src_t = 0;
    float d_t = 1e30f;
    if (t < cnt) {
      int eid = eids[start + cb + t];
      src_t = ei[eid];
      d_t = de[eid];
    }
    for (int i = 0; i < cnt; ++i) {
      int src = __shfl(src_t, i);
      float dd = __shfl(d_t, i);
      uint ku = *(const uint*)&knb[(size_t)src * DDIM + 2 * t];
      uint vu = *(const uint*)&vnb[(size_t)src * DDIM + 2 * t];
      float pr = q0 * bfl(ku) + q1 * bfh(ku);
      bool nr = dd < CUTF;  // wave-uniform
      float rb = 0.f;
      if (nr) {
        rb = (t < NRAD) ? rbf_fill(dd, t) : 0.f;
        rbl[w][t] = rb;
        pr = fmaf(rbl[w][j0], qel[w][j0][h], pr);
        pr = fmaf(rbl[w][j0 + 16], qel[w][j0 + 16][h], pr);
        pr = fmaf(rbl[w][j0 + 32], qel[w][j0 + 32][h], pr);
        pr = fmaf(rbl[w][j0 + 48], qel[w][j0 + 48][h], pr);
      }
      pr += __shfl_xor(pr, 1);
      pr += __shfl_xor(pr, 2);
      pr += __shfl_xor(pr, 4);
      pr += __shfl_xor(pr, 8);
      if ((t & 15) == 0)
        ael[w][h] = __expf(fminf(pr * 0.17677669529663687f, 60.f));
      float4 ae4 = *(float4*)&ael[w][0];
      float ae = (h == 0) ? ae4.x : (h == 1) ? ae4.y : (h == 2) ? ae4.z : ae4.w;
      s += ae;
      a0 = fmaf(ae, bfl(vu), a0);
      a1 = fmaf(ae, bfh(vu), a1);
      if (nr) {
        arb.x = fmaf(rb, ae4.x, arb.x);
        arb.y = fmaf(rb, ae4.y, arb.y);
        arb.z = fmaf(rb, ae4.z, arb.z);
        arb.w = fmaf(rb, ae4.w, arb.w);
      }
    }
  }

  // finalize: normalize; msg = a_norm + (arb_norm @ We)
  float4 s4 = {__shfl(s, 0), __shfl(s, 16), __shfl(s, 32), __shfl(s, 48)};
  float4 inv4 = {1.f / (s4.x + 1e-9f), 1.f / (s4.y + 1e-9f),
                 1.f / (s4.z + 1e-9f), 1.f / (s4.w + 1e-9f)};
  float invo = (h == 0) ? inv4.x : (h == 1) ? inv4.y : (h == 2) ? inv4.z : inv4.w;
  if (t < NRAD) {
    qel[w][t][0] = arb.x * inv4.x;
    qel[w][t][1] = arb.y * inv4.y;
    qel[w][t][2] = arb.z * inv4.z;
    qel[w][t][3] = arb.w * inv4.w;
  }
  a0 *= invo;
  a1 *= invo;
#pragma unroll 10
  for (int j = 0; j < NRAD; ++j) {
    float ar = qel[w][j][h];
    uint wu = *(const uint*)&Wel[j * DDIM + 2 * t];
    a0 = fmaf(ar, bfl(wu), a0);
    a1 = fmaf(ar, bfh(wu), a1);
  }
  uint pk = (uint)f2bf(a0) | ((uint)f2bf(a1) << 16);
  *(uint*)&msgb[(size_t)n * DDIM + 2 * t] = pk;
}

// ---------------- graph sum (batch is sorted): 64 nodes/block, boundary atomics ----------------

#define GS_NODES 64
__global__ void k_graphsum(const float* __restrict__ x, const int* __restrict__ batch,
                           float* __restrict__ g) {
  int t = threadIdx.x;  // 128 dims
  int n0 = blockIdx.x * GS_NODES;
  int nend = n0 + GS_NODES;
  if (nend > NN) nend = NN;
  if (n0 >= NN) return;
  float acc = 0.f;
  int cur = batch[n0];
  for (int n = n0; n < nend; ++n) {
    int bb = batch[n];
    if (bb != cur) {
      atomicAdd(&g[(size_t)cur * DDIM + t], acc);
      acc = 0.f;
      cur = bb;
    }
    acc += x[(size_t)n * DDIM + t];
  }
  atomicAdd(&g[(size_t)cur * DDIM + t], acc);
}

// ---------------- output projection ----------------

__global__ void k_out(const float* __restrict__ g, const float* __restrict__ W,
                      const float* __restrict__ b, float* __restrict__ out) {
  int idx = blockIdx.x * blockDim.x + threadIdx.x;
  if (idx >= NGRAPH * DOUT) return;
  int r = idx / DOUT, c = idx % DOUT;
  float acc = b[c];
#pragma unroll 8
  for (int k = 0; k < DDIM; ++k) acc = fmaf(g[r * DDIM + k], W[k * DOUT + c], acc);
  out[idx] = acc;
}

// ---------------- launch ----------------

extern "C" void kernel_launch(void* const* d_in, const int* in_sizes, int n_in,
                              void* d_out, int out_size, void* d_ws, size_t ws_size,
                              hipStream_t stream) {
  const float* pos = (const float*)d_in[0];
  const int* at = (const int*)d_in[1];
  const int* ei = (const int*)d_in[2];
  const int* batch = (const int*)d_in[3];
  const float* emb = (const float*)d_in[4];
  const float* W_init = (const float*)d_in[5];
  const float* b_init = (const float*)d_in[6];
  const float* Wq = (const float*)d_in[7];
  const float* Wk = (const float*)d_in[8];
  const float* Wv = (const float*)d_in[9];
  const float* We = (const float*)d_in[10];
  const float* Wo = (const float*)d_in[11];
  const float* Wm1 = (const float*)d_in[12];
  const float* bm1 = (const float*)d_in[13];
  const float* Wm2 = (const float*)d_in[14];
  const float* bm2 = (const float*)d_in[15];
  const float* ln_g = (const float*)d_in[16];
  const float* ln_b = (const float*)d_in[17];
  const float* W_out = (const float*)d_in[18];
  const float* b_out = (const float*)d_in[19];
  float* out = (float*)d_out;

  const size_t ND = (size_t)NN * DDIM;  // 6.4M
  float* x = (float*)d_ws;              // f32 ND
  ushort* qnb = (ushort*)(x + ND);      // bf16 ND (alias hb)
  ushort* knb = qnb + ND;               // bf16 ND (alias h2)
  ushort* vnb = knb + ND;               // bf16 ND
  ushort* msgb = vnb + ND;              // bf16 ND
  ushort* qe = msgb + ND;               // bf16 NN*200
  ushort* Wtb = qe + (size_t)NN * 200;  // bf16 12*16384
  float* de = (float*)(Wtb + 12 * 16384);  // f32 NE
  int* deg = (int*)(de + NE);
  int* cursor = deg + NN;
  int* rowptr = cursor + NN;
  int* eids = rowptr + NN + 64;
  float* gb = (float*)(eids + NE);
  // total ~94 MB

  ushort* hb = qnb;
  ushort* h2 = knb;

  k_wconv<<<12 * 16384 / 256, 256, 0, stream>>>(Wq, Wk, Wv, Wo, Wm1, Wm2, Wtb);
  k_fill_i<<<(NN + 255) / 256, 256, 0, stream>>>(deg, 0, NN);
  k_init<<<(NN * DDIM + 255) / 256, 256, 0, stream>>>(pos, at, emb, W_init, b_init, x);
  k_edge<<<(NE + 255) / 256, 256, 0, stream>>>(pos, ei, de, deg);
  k_scan<<<1, 1024, 0, stream>>>(deg, rowptr, cursor);
  k_scatter<<<(NE + 255) / 256, 256, 0, stream>>>(ei, cursor, eids);

  const int gg = (NN + 127) / 128;  // 391
  for (int l = 0; l < 2; ++l) {
    const ushort* Wt_l = Wtb + (size_t)l * 6 * 16384;
    const float* We_l = We + (size_t)l * NRAD * DDIM;

    k_qkv<<<gg, 256, 0, stream>>>(x, Wt_l, qnb, knb, vnb);
    k_qe<<<NN / 8, 256, 0, stream>>>(qnb, We_l, qe);
    k_attn3<<<NN / 4, 256, 0, stream>>>(qnb, knb, vnb, qe, de, ei, rowptr, eids, We_l, msgb);

    // x += msg@Wo, fused layernorm -> hb
    k_gemm2<false, false, true, true><<<gg, 256, 0, stream>>>(
        msgb, Wt_l + 3 * 16384, nullptr, x, x,
        ln_g + (size_t)l * DDIM, ln_b + (size_t)l * DDIM, hb);
    // h2 = gelu(hb@Wm1 + bm1)
    k_gemm2<true, true, false, false><<<gg, 256, 0, stream>>>(
        hb, Wt_l + 4 * 16384, bm1 + (size_t)l * DDIM, nullptr, h2, nullptr, nullptr, nullptr);
    // x += h2@Wm2 + bm2
    k_gemm2<true, false, true, false><<<gg, 256, 0, stream>>>(
        h2, Wt_l + 5 * 16384, bm2 + (size_t)l * DDIM, x, x, nullptr, nullptr, nullptr);
  }

  k_fill_f<<<(NGRAPH * DDIM + 255) / 256, 256, 0, stream>>>(gb, 0.f, NGRAPH * DDIM);
  k_graphsum<<<(NN + GS_NODES - 1) / GS_NODES, 128, 0, stream>>>(x, batch, gb);
  k_out<<<(NGRAPH * DOUT + 255) / 256, 256, 0, stream>>>(gb, W_out, b_out, out);
}

// Round 6
// 549.593 us; speedup vs baseline: 3.7667x; 1.1857x over previous
//
#include <hip/hip_runtime.h>
#include <math.h>

#define NN 50000
#define NE 400000
#define DDIM 128
#define NHEAD 4
#define NRAD 50
#define NGRAPH 100
#define TEMB 32
#define DOUT 512
#define CUTF 6.0f
#define PI_F 3.14159265358979323846f

#define SCAN_N ((NN + 255) / 256)  // 196 scan blocks

typedef unsigned int uint;
typedef unsigned short ushort;
typedef __attribute__((ext_vector_type(8))) short short8;
typedef __attribute__((ext_vector_type(4))) float f32x4;

// ---------------- helpers ----------------

__device__ __forceinline__ float gelu_tanh(float v) {
  float u = 0.7978845608028654f * (v + 0.044715f * v * v * v);
  return 0.5f * v * (1.0f + tanhf(u));
}

__device__ __forceinline__ ushort f2bf(float f) {  // RNE
  uint u = __float_as_uint(f);
  uint r = (u + 0x7fffu + ((u >> 16) & 1u)) >> 16;
  return (ushort)r;
}
__device__ __forceinline__ float bfl(uint u) { return __uint_as_float(u << 16); }
__device__ __forceinline__ float bfh(uint u) { return __uint_as_float(u & 0xffff0000u); }

__global__ void k_fill_f(float* p, float v, int n) {
  int i = blockIdx.x * blockDim.x + threadIdx.x;
  if (i < n) p[i] = v;
}
__global__ void k_fill_i(int* p, int v, int n) {
  int i = blockIdx.x * blockDim.x + threadIdx.x;
  if (i < n) p[i] = v;
}

// ---------------- weight pre-convert + transpose: Wtb[l][fam][c][k] bf16 ----------------

__global__ void k_wconv(const float* __restrict__ Wq, const float* __restrict__ Wk,
                        const float* __restrict__ Wv, const float* __restrict__ Wo,
                        const float* __restrict__ Wm1, const float* __restrict__ Wm2,
                        ushort* __restrict__ Wtb) {
  int idx = blockIdx.x * 256 + threadIdx.x;  // 12*16384
  int m = idx >> 14;
  int r = idx & 16383;
  int c = r >> 7, k = r & 127;
  int l = m / 6, fam = m % 6;
  const float* src = fam == 0 ? Wq : fam == 1 ? Wk : fam == 2 ? Wv
                   : fam == 3 ? Wo : fam == 4 ? Wm1 : Wm2;
  Wtb[idx] = f2bf(src[l * 16384 + k * 128 + c]);
}

// ---------------- init: x = [emb[at], pos] @ W_init + b ----------------

__global__ void k_init(const float* __restrict__ pos, const int* __restrict__ at,
                       const float* __restrict__ emb, const float* __restrict__ W,
                       const float* __restrict__ b, float* __restrict__ x) {
  int idx = blockIdx.x * blockDim.x + threadIdx.x;
  if (idx >= NN * DDIM) return;
  int n = idx >> 7, c = idx & 127;
  const float* er = emb + (size_t)at[n] * TEMB;
  float acc = b[c];
#pragma unroll
  for (int t = 0; t < TEMB; ++t) acc = fmaf(er[t], W[t * DDIM + c], acc);
  acc = fmaf(pos[n * 3 + 0], W[(TEMB + 0) * DDIM + c], acc);
  acc = fmaf(pos[n * 3 + 1], W[(TEMB + 1) * DDIM + c], acc);
  acc = fmaf(pos[n * 3 + 2], W[(TEMB + 2) * DDIM + c], acc);
  x[idx] = acc;
}

// ---------------- per-edge distance + degree histogram (fused) ----------------

__global__ void k_edge(const float* __restrict__ pos, const int* __restrict__ ei,
                       float* __restrict__ de, int* __restrict__ deg) {
  int e = blockIdx.x * blockDim.x + threadIdx.x;
  if (e >= NE) return;
  int s = ei[e], t = ei[NE + e];
  float dx = pos[s * 3 + 0] - pos[t * 3 + 0] + 1e-8f;
  float dy = pos[s * 3 + 1] - pos[t * 3 + 1] + 1e-8f;
  float dz = pos[s * 3 + 2] - pos[t * 3 + 2] + 1e-8f;
  de[e] = sqrtf(dx * dx + dy * dy + dz * dz);
  atomicAdd(&deg[t], 1);
}

// ---------------- CSR build: parallel 3-pass exclusive scan ----------------

__global__ void k_scan1(const int* __restrict__ deg, int* __restrict__ bsum) {
  __shared__ int red[256];
  int i = blockIdx.x * 256 + threadIdx.x;
  red[threadIdx.x] = (i < NN) ? deg[i] : 0;
  __syncthreads();
  for (int off = 128; off > 0; off >>= 1) {
    if (threadIdx.x < off) red[threadIdx.x] += red[threadIdx.x + off];
    __syncthreads();
  }
  if (threadIdx.x == 0) bsum[blockIdx.x] = red[0];
}

__global__ void k_scan2(int* __restrict__ bsum) {  // 1 block, 256 threads >= SCAN_N
  __shared__ int sh[256];
  int t = threadIdx.x;
  int v = (t < SCAN_N) ? bsum[t] : 0;
  sh[t] = v;
  __syncthreads();
  for (int off = 1; off < 256; off <<= 1) {
    int u = (t >= off) ? sh[t - off] : 0;
    __syncthreads();
    sh[t] += u;
    __syncthreads();
  }
  if (t < SCAN_N) bsum[t] = (t == 0) ? 0 : sh[t - 1];
}

__global__ void k_scan3(const int* __restrict__ deg, const int* __restrict__ bsum,
                        int* __restrict__ rowptr, int* __restrict__ cursor) {
  __shared__ int sh[256];
  int t = threadIdx.x;
  int i = blockIdx.x * 256 + t;
  int v = (i < NN) ? deg[i] : 0;
  sh[t] = v;
  __syncthreads();
  for (int off = 1; off < 256; off <<= 1) {
    int u = (t >= off) ? sh[t - off] : 0;
    __syncthreads();
    sh[t] += u;
    __syncthreads();
  }
  int excl = bsum[blockIdx.x] + sh[t] - v;
  if (i < NN) {
    rowptr[i] = excl;
    cursor[i] = excl;
    if (i == NN - 1) rowptr[NN] = excl + v;
  }
}

__global__ void k_scatter(const int* __restrict__ ei, int* __restrict__ cursor,
                          int* __restrict__ eids) {
  int e = blockIdx.x * blockDim.x + threadIdx.x;
  if (e >= NE) return;
  int idx = atomicAdd(&cursor[ei[NE + e]], 1);
  eids[idx] = e;
}

// ---------------- fused QKV GEMM: stage x once, 3 weights ----------------
// block 256 = 4 waves; 128 rows x 128 cols; 16x16x32 bf16 MFMA; wave owns 32 rows.

__global__ __launch_bounds__(256) void k_qkv(
    const float* __restrict__ x, const ushort* __restrict__ Wt3,
    ushort* __restrict__ qo, ushort* __restrict__ ko, ushort* __restrict__ vo) {
  __shared__ ushort Al[128 * 128];
  __shared__ ushort Wl[128 * 128];
  const int tid = threadIdx.x;
  const int r0 = blockIdx.x * 128;

  for (int i = tid; i < 128 * 16; i += 256) {
    int r = i >> 4, g = i & 15;
    int gr = r0 + r;
    float4 f0 = {0, 0, 0, 0}, f1 = {0, 0, 0, 0};
    if (gr < NN) {
      f0 = *(const float4*)&x[(size_t)gr * 128 + g * 8];
      f1 = *(const float4*)&x[(size_t)gr * 128 + g * 8 + 4];
    }
    int gs = g ^ (r & 7);
    ushort4 u0 = {f2bf(f0.x), f2bf(f0.y), f2bf(f0.z), f2bf(f0.w)};
    ushort4 u1 = {f2bf(f1.x), f2bf(f1.y), f2bf(f1.z), f2bf(f1.w)};
    *(ushort4*)&Al[r * 128 + gs * 8] = u0;
    *(ushort4*)&Al[r * 128 + gs * 8 + 4] = u1;
  }

  const int w = tid >> 6, l = tid & 63;
  const int lg = l >> 4, lr = l & 15;

  for (int m = 0; m < 3; ++m) {
    for (int i = tid; i < 128 * 16; i += 256) {
      int c = i >> 4, g = i & 15;
      ushort4 w0 = *(const ushort4*)&Wt3[m * 16384 + c * 128 + g * 8];
      ushort4 w1 = *(const ushort4*)&Wt3[m * 16384 + c * 128 + g * 8 + 4];
      int gs = g ^ (c & 7);
      *(ushort4*)&Wl[c * 128 + gs * 8] = w0;
      *(ushort4*)&Wl[c * 128 + gs * 8 + 4] = w1;
    }
    __syncthreads();

    f32x4 acc[2][8];
#pragma unroll
    for (int rt = 0; rt < 2; ++rt)
#pragma unroll
      for (int ct = 0; ct < 8; ++ct) acc[rt][ct] = (f32x4){0.f, 0.f, 0.f, 0.f};

#pragma unroll
    for (int ks = 0; ks < 4; ++ks) {
      short8 af[2];
#pragma unroll
      for (int rt = 0; rt < 2; ++rt) {
        int arow = w * 32 + rt * 16 + lr;
        int ga = (ks * 4 + lg) ^ (arow & 7);
        af[rt] = *(const short8*)&Al[arow * 128 + ga * 8];
      }
#pragma unroll
      for (int ct = 0; ct < 8; ++ct) {
        int col = ct * 16 + lr;
        int gb = (ks * 4 + lg) ^ (col & 7);
        short8 bf = *(const short8*)&Wl[col * 128 + gb * 8];
#pragma unroll
        for (int rt = 0; rt < 2; ++rt)
          acc[rt][ct] = __builtin_amdgcn_mfma_f32_16x16x32_bf16(af[rt], bf, acc[rt][ct], 0, 0, 0);
      }
    }

    ushort* o = (m == 0) ? qo : (m == 1) ? ko : vo;
#pragma unroll
    for (int rt = 0; rt < 2; ++rt)
#pragma unroll
      for (int ct = 0; ct < 8; ++ct) {
        int col = ct * 16 + lr;
#pragma unroll
        for (int r = 0; r < 4; ++r) {
          int row = r0 + w * 32 + rt * 16 + lg * 4 + r;
          if (row < NN) o[(size_t)row * 128 + col] = f2bf(acc[rt][ct][r]);
        }
      }
    __syncthreads();
  }
}

// ---------------- general GEMM: out = act(A@W + bias) (+resid) (+fused LN), A bf16 ----------------

template <bool BIAS, bool GELU, bool RESID, bool LNF>
__global__ __launch_bounds__(256) void k_gemm2(
    const ushort* __restrict__ A, const ushort* __restrict__ Wt,
    const float* __restrict__ bias, const float* __restrict__ resid,
    void* __restrict__ outp, const float* __restrict__ lng,
    const float* __restrict__ lnb, ushort* __restrict__ lnout) {
  __shared__ ushort Al[128 * 128];
  __shared__ ushort Wl[128 * 128];
  const int tid = threadIdx.x;
  const int r0 = blockIdx.x * 128;

  for (int i = tid; i < 128 * 16; i += 256) {
    int r = i >> 4, g = i & 15;
    int gr = r0 + r;
    ushort4 v0 = {0, 0, 0, 0}, v1 = {0, 0, 0, 0};
    if (gr < NN) {
      v0 = *(const ushort4*)&A[(size_t)gr * 128 + g * 8];
      v1 = *(const ushort4*)&A[(size_t)gr * 128 + g * 8 + 4];
    }
    int gs = g ^ (r & 7);
    *(ushort4*)&Al[r * 128 + gs * 8] = v0;
    *(ushort4*)&Al[r * 128 + gs * 8 + 4] = v1;
  }
  for (int i = tid; i < 128 * 16; i += 256) {
    int c = i >> 4, g = i & 15;
    ushort4 w0 = *(const ushort4*)&Wt[c * 128 + g * 8];
    ushort4 w1 = *(const ushort4*)&Wt[c * 128 + g * 8 + 4];
    int gs = g ^ (c & 7);
    *(ushort4*)&Wl[c * 128 + gs * 8] = w0;
    *(ushort4*)&Wl[c * 128 + gs * 8 + 4] = w1;
  }
  __syncthreads();

  const int w = tid >> 6, l = tid & 63;
  const int lg = l >> 4, lr = l & 15;
  f32x4 acc[2][8];
#pragma unroll
  for (int rt = 0; rt < 2; ++rt)
#pragma unroll
    for (int ct = 0; ct < 8; ++ct) acc[rt][ct] = (f32x4){0.f, 0.f, 0.f, 0.f};

#pragma unroll
  for (int ks = 0; ks < 4; ++ks) {
    short8 af[2];
#pragma unroll
    for (int rt = 0; rt < 2; ++rt) {
      int arow = w * 32 + rt * 16 + lr;
      int ga = (ks * 4 + lg) ^ (arow & 7);
      af[rt] = *(const short8*)&Al[arow * 128 + ga * 8];
    }
#pragma unroll
    for (int ct = 0; ct < 8; ++ct) {
      int col = ct * 16 + lr;
      int gb = (ks * 4 + lg) ^ (col & 7);
      short8 bf = *(const short8*)&Wl[col * 128 + gb * 8];
#pragma unroll
      for (int rt = 0; rt < 2; ++rt)
        acc[rt][ct] = __builtin_amdgcn_mfma_f32_16x16x32_bf16(af[rt], bf, acc[rt][ct], 0, 0, 0);
    }
  }

#pragma unroll
  for (int rt = 0; rt < 2; ++rt)
#pragma unroll
    for (int r = 0; r < 4; ++r) {
      int row = r0 + w * 32 + rt * 16 + lg * 4 + r;
      bool ok = row < NN;  // uniform across the 16-lane lr group
      float v[8];
#pragma unroll
      for (int ct = 0; ct < 8; ++ct) {
        int col = ct * 16 + lr;
        float vv = acc[rt][ct][r];
        if (BIAS) vv += bias[col];
        if (GELU) vv = gelu_tanh(vv);
        if (RESID) vv += ok ? resid[(size_t)row * 128 + col] : 0.f;
        v[ct] = vv;
      }
      if (RESID || LNF) {
        if (ok)
#pragma unroll
          for (int ct = 0; ct < 8; ++ct)
            ((float*)outp)[(size_t)row * 128 + ct * 16 + lr] = v[ct];
      } else {
        if (ok)
#pragma unroll
          for (int ct = 0; ct < 8; ++ct)
            ((ushort*)outp)[(size_t)row * 128 + ct * 16 + lr] = f2bf(v[ct]);
      }
      if (LNF) {
        float s = 0.f, ss = 0.f;
#pragma unroll
        for (int ct = 0; ct < 8; ++ct) {
          s += v[ct];
          ss = fmaf(v[ct], v[ct], ss);
        }
#pragma unroll
        for (int msk = 8; msk >= 1; msk >>= 1) {
          s += __shfl_xor(s, msk);
          ss += __shfl_xor(ss, msk);
        }
        float mean = s * (1.0f / DDIM);
        float var = ss * (1.0f / DDIM) - mean * mean;
        float inv = rsqrtf(var + 1e-5f);
        if (ok)
#pragma unroll
          for (int ct = 0; ct < 8; ++ct) {
            int col = ct * 16 + lr;
            lnout[(size_t)row * 128 + col] =
                f2bf((v[ct] - mean) * inv * lng[col] + lnb[col]);
          }
      }
    }
}

// ---------------- qe precompute: qe[n][j][h] ----------------

__global__ __launch_bounds__(256) void k_qe(const ushort* __restrict__ qnb,
                                            const float* __restrict__ We,
                                            ushort* __restrict__ qe) {
  __shared__ float Wlds[NRAD][DDIM + 1];
  __shared__ float qlds[4][DDIM];
  int tid = threadIdx.x;
  for (int i = tid; i < NRAD * DDIM; i += 256) Wlds[i / DDIM][i % DDIM] = We[i];
  __syncthreads();
  int w = tid >> 6, t = tid & 63;
  for (int rep = 0; rep < 2; ++rep) {
    int n = blockIdx.x * 8 + rep * 4 + w;
    uint qu = *(const uint*)&qnb[(size_t)n * DDIM + 2 * t];
    qlds[w][2 * t] = bfl(qu);
    qlds[w][2 * t + 1] = bfh(qu);
    if (t < NRAD) {
      float e0 = 0.f, e1 = 0.f, e2 = 0.f, e3 = 0.f;
#pragma unroll
      for (int d = 0; d < 32; ++d) e0 = fmaf(Wlds[t][d], qlds[w][d], e0);
#pragma unroll
      for (int d = 32; d < 64; ++d) e1 = fmaf(Wlds[t][d], qlds[w][d], e1);
#pragma unroll
      for (int d = 64; d < 96; ++d) e2 = fmaf(Wlds[t][d], qlds[w][d], e2);
#pragma unroll
      for (int d = 96; d < 128; ++d) e3 = fmaf(Wlds[t][d], qlds[w][d], e3);
      ushort4 o = {f2bf(e0), f2bf(e1), f2bf(e2), f2bf(e3)};
      *(ushort4*)&qe[(size_t)n * (NRAD * 4) + 4 * t] = o;
    }
  }
}

// ---------------- fused attention v3: single-pass (no running max), per-node wave ----------------

__device__ __forceinline__ float rbf_fill(float d, int j) {
  const float step = CUTF / (NRAD - 1);
  const float gamma = (NRAD / CUTF) * (NRAD / CUTF);
  float mu = j * step;
  float dm = d - mu;
  float env = 0.5f * (__cosf(PI_F * d / CUTF) + 1.0f);
  return __expf(-gamma * dm * dm) * env;
}

__global__ __launch_bounds__(256) void k_attn3(
    const ushort* __restrict__ qnb, const ushort* __restrict__ knb,
    const ushort* __restrict__ vnb, const ushort* __restrict__ qe,
    const float* __restrict__ de, const int* __restrict__ ei,
    const int* __restrict__ rowptr, const int* __restrict__ eids,
    const float* __restrict__ We, ushort* __restrict__ msgb) {
  __shared__ float qel[4][64][4];   // [wave][j(padded)][head]; reused for arbn in epilogue
  __shared__ float rbl[4][64];
  __shared__ float ael[4][4];
  __shared__ ushort Wel[NRAD * DDIM];
  const int tid = threadIdx.x;
  for (int i = tid; i < NRAD * DDIM; i += 256) Wel[i] = f2bf(We[i]);
  __syncthreads();

  const int w = tid >> 6, t = tid & 63;
  const int n = blockIdx.x * 4 + w;
  const int h = t >> 4;
  uint qu = *(const uint*)&qnb[(size_t)n * DDIM + 2 * t];
  const float q0 = bfl(qu), q1 = bfh(qu);
  if (t < NRAD) {
    ushort4 qv = *(const ushort4*)&qe[(size_t)n * (NRAD * 4) + 4 * t];
    qel[w][t][0] = bfl(qv.x);
    qel[w][t][1] = bfl(qv.y);
    qel[w][t][2] = bfl(qv.z);
    qel[w][t][3] = bfl(qv.w);
  } else {
    qel[w][t][0] = 0.f; qel[w][t][1] = 0.f; qel[w][t][2] = 0.f; qel[w][t][3] = 0.f;
  }
  const int start = rowptr[n];
  const int deg = rowptr[n + 1] - start;

  float s = 0.f, a0 = 0.f, a1 = 0.f;
  float4 arb = {0.f, 0.f, 0.f, 0.f};
  const int j0 = t & 15;

  for (int cb = 0; cb < deg; cb += 64) {
    int cnt = min(deg - cb, 64);
    int src_t = 0;
    float d_t = 1e30f;
    if (t < cnt) {
      int eid = eids[start + cb + t];
      src_t = ei[eid];
      d_t = de[eid];
    }
    for (int i = 0; i < cnt; ++i) {
      int src = __shfl(src_t, i);
      float dd = __shfl(d_t, i);
      uint ku = *(const uint*)&knb[(size_t)src * DDIM + 2 * t];
      uint vu = *(const uint*)&vnb[(size_t)src * DDIM + 2 * t];
      float pr = q0 * bfl(ku) + q1 * bfh(ku);
      bool nr = dd < CUTF;  // wave-uniform
      float rb = 0.f;
      if (nr) {
        rb = (t < NRAD) ? rbf_fill(dd, t) : 0.f;
        rbl[w][t] = rb;
        pr = fmaf(rbl[w][j0], qel[w][j0][h], pr);
        pr = fmaf(rbl[w][j0 + 16], qel[w][j0 + 16][h], pr);
        pr = fmaf(rbl[w][j0 + 32], qel[w][j0 + 32][h], pr);
        pr = fmaf(rbl[w][j0 + 48], qel[w][j0 + 48][h], pr);
      }
      pr += __shfl_xor(pr, 1);
      pr += __shfl_xor(pr, 2);
      pr += __shfl_xor(pr, 4);
      pr += __shfl_xor(pr, 8);
      if ((t & 15) == 0)
        ael[w][h] = __expf(fminf(pr * 0.17677669529663687f, 60.f));
      float4 ae4 = *(float4*)&ael[w][0];
      float ae = (h == 0) ? ae4.x : (h == 1) ? ae4.y : (h == 2) ? ae4.z : ae4.w;
      s += ae;
      a0 = fmaf(ae, bfl(vu), a0);
      a1 = fmaf(ae, bfh(vu), a1);
      if (nr) {
        arb.x = fmaf(rb, ae4.x, arb.x);
        arb.y = fmaf(rb, ae4.y, arb.y);
        arb.z = fmaf(rb, ae4.z, arb.z);
        arb.w = fmaf(rb, ae4.w, arb.w);
      }
    }
  }

  // finalize: normalize; msg = a_norm + (arb_norm @ We)
  float4 s4 = {__shfl(s, 0), __shfl(s, 16), __shfl(s, 32), __shfl(s, 48)};
  float4 inv4 = {1.f / (s4.x + 1e-9f), 1.f / (s4.y + 1e-9f),
                 1.f / (s4.z + 1e-9f), 1.f / (s4.w + 1e-9f)};
  float invo = (h == 0) ? inv4.x : (h == 1) ? inv4.y : (h == 2) ? inv4.z : inv4.w;
  if (t < NRAD) {
    qel[w][t][0] = arb.x * inv4.x;
    qel[w][t][1] = arb.y * inv4.y;
    qel[w][t][2] = arb.z * inv4.z;
    qel[w][t][3] = arb.w * inv4.w;
  }
  a0 *= invo;
  a1 *= invo;
#pragma unroll 10
  for (int j = 0; j < NRAD; ++j) {
    float ar = qel[w][j][h];
    uint wu = *(const uint*)&Wel[j * DDIM + 2 * t];
    a0 = fmaf(ar, bfl(wu), a0);
    a1 = fmaf(ar, bfh(wu), a1);
  }
  uint pk = (uint)f2bf(a0) | ((uint)f2bf(a1) << 16);
  *(uint*)&msgb[(size_t)n * DDIM + 2 * t] = pk;
}

// ---------------- graph sum (batch is sorted): 64 nodes/block, boundary atomics ----------------

#define GS_NODES 64
__global__ void k_graphsum(const float* __restrict__ x, const int* __restrict__ batch,
                           float* __restrict__ g) {
  int t = threadIdx.x;  // 128 dims
  int n0 = blockIdx.x * GS_NODES;
  int nend = n0 + GS_NODES;
  if (nend > NN) nend = NN;
  if (n0 >= NN) return;
  float acc = 0.f;
  int cur = batch[n0];
  for (int n = n0; n < nend; ++n) {
    int bb = batch[n];
    if (bb != cur) {
      atomicAdd(&g[(size_t)cur * DDIM + t], acc);
      acc = 0.f;
      cur = bb;
    }
    acc += x[(size_t)n * DDIM + t];
  }
  atomicAdd(&g[(size_t)cur * DDIM + t], acc);
}

// ---------------- output projection ----------------

__global__ void k_out(const float* __restrict__ g, const float* __restrict__ W,
                      const float* __restrict__ b, float* __restrict__ out) {
  int idx = blockIdx.x * blockDim.x + threadIdx.x;
  if (idx >= NGRAPH * DOUT) return;
  int r = idx / DOUT, c = idx % DOUT;
  float acc = b[c];
#pragma unroll 8
  for (int k = 0; k < DDIM; ++k) acc = fmaf(g[r * DDIM + k], W[k * DOUT + c], acc);
  out[idx] = acc;
}

// ---------------- launch ----------------

extern "C" void kernel_launch(void* const* d_in, const int* in_sizes, int n_in,
                              void* d_out, int out_size, void* d_ws, size_t ws_size,
                              hipStream_t stream) {
  const float* pos = (const float*)d_in[0];
  const int* at = (const int*)d_in[1];
  const int* ei = (const int*)d_in[2];
  const int* batch = (const int*)d_in[3];
  const float* emb = (const float*)d_in[4];
  const float* W_init = (const float*)d_in[5];
  const float* b_init = (const float*)d_in[6];
  const float* Wq = (const float*)d_in[7];
  const float* Wk = (const float*)d_in[8];
  const float* Wv = (const float*)d_in[9];
  const float* We = (const float*)d_in[10];
  const float* Wo = (const float*)d_in[11];
  const float* Wm1 = (const float*)d_in[12];
  const float* bm1 = (const float*)d_in[13];
  const float* Wm2 = (const float*)d_in[14];
  const float* bm2 = (const float*)d_in[15];
  const float* ln_g = (const float*)d_in[16];
  const float* ln_b = (const float*)d_in[17];
  const float* W_out = (const float*)d_in[18];
  const float* b_out = (const float*)d_in[19];
  float* out = (float*)d_out;

  const size_t ND = (size_t)NN * DDIM;  // 6.4M
  float* x = (float*)d_ws;              // f32 ND
  ushort* qnb = (ushort*)(x + ND);      // bf16 ND (alias hb)
  ushort* knb = qnb + ND;               // bf16 ND (alias h2)
  ushort* vnb = knb + ND;               // bf16 ND
  ushort* msgb = vnb + ND;              // bf16 ND
  ushort* qe = msgb + ND;               // bf16 NN*200
  ushort* Wtb = qe + (size_t)NN * 200;  // bf16 12*16384
  float* de = (float*)(Wtb + 12 * 16384);  // f32 NE
  int* deg = (int*)(de + NE);
  int* cursor = deg + NN;
  int* rowptr = cursor + NN;
  int* eids = rowptr + NN + 64;
  float* gb = (float*)(eids + NE);      // NG*DDIM
  int* bsum = (int*)(gb + NGRAPH * DDIM);  // SCAN_N
  // total ~94 MB

  ushort* hb = qnb;
  ushort* h2 = knb;

  k_wconv<<<12 * 16384 / 256, 256, 0, stream>>>(Wq, Wk, Wv, Wo, Wm1, Wm2, Wtb);
  k_fill_i<<<(NN + 255) / 256, 256, 0, stream>>>(deg, 0, NN);
  k_init<<<(NN * DDIM + 255) / 256, 256, 0, stream>>>(pos, at, emb, W_init, b_init, x);
  k_edge<<<(NE + 255) / 256, 256, 0, stream>>>(pos, ei, de, deg);
  k_scan1<<<SCAN_N, 256, 0, stream>>>(deg, bsum);
  k_scan2<<<1, 256, 0, stream>>>(bsum);
  k_scan3<<<SCAN_N, 256, 0, stream>>>(deg, bsum, rowptr, cursor);
  k_scatter<<<(NE + 255) / 256, 256, 0, stream>>>(ei, cursor, eids);

  const int gg = (NN + 127) / 128;  // 391
  for (int l = 0; l < 2; ++l) {
    const ushort* Wt_l = Wtb + (size_t)l * 6 * 16384;
    const float* We_l = We + (size_t)l * NRAD * DDIM;

    k_qkv<<<gg, 256, 0, stream>>>(x, Wt_l, qnb, knb, vnb);
    k_qe<<<NN / 8, 256, 0, stream>>>(qnb, We_l, qe);
    k_attn3<<<NN / 4, 256, 0, stream>>>(qnb, knb, vnb, qe, de, ei, rowptr, eids, We_l, msgb);

    // x += msg@Wo, fused layernorm -> hb
    k_gemm2<false, false, true, true><<<gg, 256, 0, stream>>>(
        msgb, Wt_l + 3 * 16384, nullptr, x, x,
        ln_g + (size_t)l * DDIM, ln_b + (size_t)l * DDIM, hb);
    // h2 = gelu(hb@Wm1 + bm1)
    k_gemm2<true, true, false, false><<<gg, 256, 0, stream>>>(
        hb, Wt_l + 4 * 16384, bm1 + (size_t)l * DDIM, nullptr, h2, nullptr, nullptr, nullptr);
    // x += h2@Wm2 + bm2
    k_gemm2<true, false, true, false><<<gg, 256, 0, stream>>>(
        h2, Wt_l + 5 * 16384, bm2 + (size_t)l * DDIM, x, x, nullptr, nullptr, nullptr);
  }

  k_fill_f<<<(NGRAPH * DDIM + 255) / 256, 256, 0, stream>>>(gb, 0.f, NGRAPH * DDIM);
  k_graphsum<<<(NN + GS_NODES - 1) / GS_NODES, 128, 0, stream>>>(x, batch, gb);
  k_out<<<(NGRAPH * DOUT + 255) / 256, 256, 0, stream>>>(gb, W_out, b_out, out);
}

// Round 7
// 505.968 us; speedup vs baseline: 4.0914x; 1.0862x over previous
//
#include <hip/hip_runtime.h>
#include <math.h>

#define NN 50000
#define NE 400000
#define DDIM 128
#define NHEAD 4
#define NRAD 50
#define NGRAPH 100
#define TEMB 32
#define DOUT 512
#define CUTF 6.0f
#define PI_F 3.14159265358979323846f

#define SCAN_N ((NN + 255) / 256)  // 196 scan blocks

typedef unsigned int uint;
typedef unsigned short ushort;
typedef __attribute__((ext_vector_type(8))) short short8;
typedef __attribute__((ext_vector_type(4))) float f32x4;

// ---------------- helpers ----------------

__device__ __forceinline__ float gelu_tanh(float v) {
  float u = 0.7978845608028654f * (v + 0.044715f * v * v * v);
  return 0.5f * v * (1.0f + tanhf(u));
}

__device__ __forceinline__ ushort f2bf(float f) {  // RNE
  uint u = __float_as_uint(f);
  uint r = (u + 0x7fffu + ((u >> 16) & 1u)) >> 16;
  return (ushort)r;
}
__device__ __forceinline__ float bfl(uint u) { return __uint_as_float(u << 16); }
__device__ __forceinline__ float bfh(uint u) { return __uint_as_float(u & 0xffff0000u); }

__global__ void k_fill_f(float* p, float v, int n) {
  int i = blockIdx.x * blockDim.x + threadIdx.x;
  if (i < n) p[i] = v;
}
__global__ void k_fill_i(int* p, int v, int n) {
  int i = blockIdx.x * blockDim.x + threadIdx.x;
  if (i < n) p[i] = v;
}

// ---------------- weight pre-convert + transpose: Wtb[l][fam][c][k] bf16 ----------------

__global__ void k_wconv(const float* __restrict__ Wq, const float* __restrict__ Wk,
                        const float* __restrict__ Wv, const float* __restrict__ Wo,
                        const float* __restrict__ Wm1, const float* __restrict__ Wm2,
                        ushort* __restrict__ Wtb) {
  int idx = blockIdx.x * 256 + threadIdx.x;  // 12*16384
  int m = idx >> 14;
  int r = idx & 16383;
  int c = r >> 7, k = r & 127;
  int l = m / 6, fam = m % 6;
  const float* src = fam == 0 ? Wq : fam == 1 ? Wk : fam == 2 ? Wv
                   : fam == 3 ? Wo : fam == 4 ? Wm1 : Wm2;
  Wtb[idx] = f2bf(src[l * 16384 + k * 128 + c]);
}

// ---------------- init: x = [emb[at], pos] @ W_init + b ----------------

__global__ void k_init(const float* __restrict__ pos, const int* __restrict__ at,
                       const float* __restrict__ emb, const float* __restrict__ W,
                       const float* __restrict__ b, float* __restrict__ x) {
  int idx = blockIdx.x * blockDim.x + threadIdx.x;
  if (idx >= NN * DDIM) return;
  int n = idx >> 7, c = idx & 127;
  const float* er = emb + (size_t)at[n] * TEMB;
  float acc = b[c];
#pragma unroll
  for (int t = 0; t < TEMB; ++t) acc = fmaf(er[t], W[t * DDIM + c], acc);
  acc = fmaf(pos[n * 3 + 0], W[(TEMB + 0) * DDIM + c], acc);
  acc = fmaf(pos[n * 3 + 1], W[(TEMB + 1) * DDIM + c], acc);
  acc = fmaf(pos[n * 3 + 2], W[(TEMB + 2) * DDIM + c], acc);
  x[idx] = acc;
}

// ---------------- per-edge distance + degree histogram (fused) ----------------

__global__ void k_edge(const float* __restrict__ pos, const int* __restrict__ ei,
                       float* __restrict__ de, int* __restrict__ deg) {
  int e = blockIdx.x * blockDim.x + threadIdx.x;
  if (e >= NE) return;
  int s = ei[e], t = ei[NE + e];
  float dx = pos[s * 3 + 0] - pos[t * 3 + 0] + 1e-8f;
  float dy = pos[s * 3 + 1] - pos[t * 3 + 1] + 1e-8f;
  float dz = pos[s * 3 + 2] - pos[t * 3 + 2] + 1e-8f;
  de[e] = sqrtf(dx * dx + dy * dy + dz * dz);
  atomicAdd(&deg[t], 1);
}

// ---------------- CSR build: parallel 3-pass exclusive scan ----------------

__global__ void k_scan1(const int* __restrict__ deg, int* __restrict__ bsum) {
  __shared__ int red[256];
  int i = blockIdx.x * 256 + threadIdx.x;
  red[threadIdx.x] = (i < NN) ? deg[i] : 0;
  __syncthreads();
  for (int off = 128; off > 0; off >>= 1) {
    if (threadIdx.x < off) red[threadIdx.x] += red[threadIdx.x + off];
    __syncthreads();
  }
  if (threadIdx.x == 0) bsum[blockIdx.x] = red[0];
}

__global__ void k_scan2(int* __restrict__ bsum) {  // 1 block, 256 threads >= SCAN_N
  __shared__ int sh[256];
  int t = threadIdx.x;
  int v = (t < SCAN_N) ? bsum[t] : 0;
  sh[t] = v;
  __syncthreads();
  for (int off = 1; off < 256; off <<= 1) {
    int u = (t >= off) ? sh[t - off] : 0;
    __syncthreads();
    sh[t] += u;
    __syncthreads();
  }
  if (t < SCAN_N) bsum[t] = (t == 0) ? 0 : sh[t - 1];
}

__global__ void k_scan3(const int* __restrict__ deg, const int* __restrict__ bsum,
                        int* __restrict__ rowptr, int* __restrict__ cnear,
                        int* __restrict__ cfar) {
  __shared__ int sh[256];
  int t = threadIdx.x;
  int i = blockIdx.x * 256 + t;
  int v = (i < NN) ? deg[i] : 0;
  sh[t] = v;
  __syncthreads();
  for (int off = 1; off < 256; off <<= 1) {
    int u = (t >= off) ? sh[t - off] : 0;
    __syncthreads();
    sh[t] += u;
    __syncthreads();
  }
  int excl = bsum[blockIdx.x] + sh[t] - v;
  if (i < NN) {
    rowptr[i] = excl;
    cnear[i] = excl;
    cfar[i] = excl + v;  // = rowptr[i+1]
    if (i == NN - 1) rowptr[NN] = excl + v;
  }
}

// scatter into near-first / far-last segmented CSR, packed records {src, d}
__global__ void k_scatter(const int* __restrict__ ei, const float* __restrict__ de,
                          int* __restrict__ cnear, int* __restrict__ cfar,
                          int2* __restrict__ er) {
  int e = blockIdx.x * blockDim.x + threadIdx.x;
  if (e >= NE) return;
  int src = ei[e], dst = ei[NE + e];
  float d = de[e];
  int idx;
  if (d < CUTF)
    idx = atomicAdd(&cnear[dst], 1);
  else
    idx = atomicSub(&cfar[dst], 1) - 1;
  er[idx] = make_int2(src, __float_as_int(d));
}

// ---------------- fused QKV GEMM: stage x once, 3 weights ----------------
// block 256 = 4 waves; 128 rows x 128 cols; 16x16x32 bf16 MFMA; wave owns 32 rows.

__global__ __launch_bounds__(256) void k_qkv(
    const float* __restrict__ x, const ushort* __restrict__ Wt3,
    ushort* __restrict__ qo, ushort* __restrict__ ko, ushort* __restrict__ vo) {
  __shared__ ushort Al[128 * 128];
  __shared__ ushort Wl[128 * 128];
  const int tid = threadIdx.x;
  const int r0 = blockIdx.x * 128;

  for (int i = tid; i < 128 * 16; i += 256) {
    int r = i >> 4, g = i & 15;
    int gr = r0 + r;
    float4 f0 = {0, 0, 0, 0}, f1 = {0, 0, 0, 0};
    if (gr < NN) {
      f0 = *(const float4*)&x[(size_t)gr * 128 + g * 8];
      f1 = *(const float4*)&x[(size_t)gr * 128 + g * 8 + 4];
    }
    int gs = g ^ (r & 7);
    ushort4 u0 = {f2bf(f0.x), f2bf(f0.y), f2bf(f0.z), f2bf(f0.w)};
    ushort4 u1 = {f2bf(f1.x), f2bf(f1.y), f2bf(f1.z), f2bf(f1.w)};
    *(ushort4*)&Al[r * 128 + gs * 8] = u0;
    *(ushort4*)&Al[r * 128 + gs * 8 + 4] = u1;
  }

  const int w = tid >> 6, l = tid & 63;
  const int lg = l >> 4, lr = l & 15;

  for (int m = 0; m < 3; ++m) {
    for (int i = tid; i < 128 * 16; i += 256) {
      int c = i >> 4, g = i & 15;
      ushort4 w0 = *(const ushort4*)&Wt3[m * 16384 + c * 128 + g * 8];
      ushort4 w1 = *(const ushort4*)&Wt3[m * 16384 + c * 128 + g * 8 + 4];
      int gs = g ^ (c & 7);
      *(ushort4*)&Wl[c * 128 + gs * 8] = w0;
      *(ushort4*)&Wl[c * 128 + gs * 8 + 4] = w1;
    }
    __syncthreads();

    f32x4 acc[2][8];
#pragma unroll
    for (int rt = 0; rt < 2; ++rt)
#pragma unroll
      for (int ct = 0; ct < 8; ++ct) acc[rt][ct] = (f32x4){0.f, 0.f, 0.f, 0.f};

#pragma unroll
    for (int ks = 0; ks < 4; ++ks) {
      short8 af[2];
#pragma unroll
      for (int rt = 0; rt < 2; ++rt) {
        int arow = w * 32 + rt * 16 + lr;
        int ga = (ks * 4 + lg) ^ (arow & 7);
        af[rt] = *(const short8*)&Al[arow * 128 + ga * 8];
      }
#pragma unroll
      for (int ct = 0; ct < 8; ++ct) {
        int col = ct * 16 + lr;
        int gb = (ks * 4 + lg) ^ (col & 7);
        short8 bf = *(const short8*)&Wl[col * 128 + gb * 8];
#pragma unroll
        for (int rt = 0; rt < 2; ++rt)
          acc[rt][ct] = __builtin_amdgcn_mfma_f32_16x16x32_bf16(af[rt], bf, acc[rt][ct], 0, 0, 0);
      }
    }

    ushort* o = (m == 0) ? qo : (m == 1) ? ko : vo;
#pragma unroll
    for (int rt = 0; rt < 2; ++rt)
#pragma unroll
      for (int ct = 0; ct < 8; ++ct) {
        int col = ct * 16 + lr;
#pragma unroll
        for (int r = 0; r < 4; ++r) {
          int row = r0 + w * 32 + rt * 16 + lg * 4 + r;
          if (row < NN) o[(size_t)row * 128 + col] = f2bf(acc[rt][ct][r]);
        }
      }
    __syncthreads();
  }
}

// ---------------- general GEMM: out = act(A@W + bias) (+resid) (+fused LN), A bf16 ----------------

template <bool BIAS, bool GELU, bool RESID, bool LNF>
__global__ __launch_bounds__(256) void k_gemm2(
    const ushort* __restrict__ A, const ushort* __restrict__ Wt,
    const float* __restrict__ bias, const float* __restrict__ resid,
    void* __restrict__ outp, const float* __restrict__ lng,
    const float* __restrict__ lnb, ushort* __restrict__ lnout) {
  __shared__ ushort Al[128 * 128];
  __shared__ ushort Wl[128 * 128];
  const int tid = threadIdx.x;
  const int r0 = blockIdx.x * 128;

  for (int i = tid; i < 128 * 16; i += 256) {
    int r = i >> 4, g = i & 15;
    int gr = r0 + r;
    ushort4 v0 = {0, 0, 0, 0}, v1 = {0, 0, 0, 0};
    if (gr < NN) {
      v0 = *(const ushort4*)&A[(size_t)gr * 128 + g * 8];
      v1 = *(const ushort4*)&A[(size_t)gr * 128 + g * 8 + 4];
    }
    int gs = g ^ (r & 7);
    *(ushort4*)&Al[r * 128 + gs * 8] = v0;
    *(ushort4*)&Al[r * 128 + gs * 8 + 4] = v1;
  }
  for (int i = tid; i < 128 * 16; i += 256) {
    int c = i >> 4, g = i & 15;
    ushort4 w0 = *(const ushort4*)&Wt[c * 128 + g * 8];
    ushort4 w1 = *(const ushort4*)&Wt[c * 128 + g * 8 + 4];
    int gs = g ^ (c & 7);
    *(ushort4*)&Wl[c * 128 + gs * 8] = w0;
    *(ushort4*)&Wl[c * 128 + gs * 8 + 4] = w1;
  }
  __syncthreads();

  const int w = tid >> 6, l = tid & 63;
  const int lg = l >> 4, lr = l & 15;
  f32x4 acc[2][8];
#pragma unroll
  for (int rt = 0; rt < 2; ++rt)
#pragma unroll
    for (int ct = 0; ct < 8; ++ct) acc[rt][ct] = (f32x4){0.f, 0.f, 0.f, 0.f};

#pragma unroll
  for (int ks = 0; ks < 4; ++ks) {
    short8 af[2];
#pragma unroll
    for (int rt = 0; rt < 2; ++rt) {
      int arow = w * 32 + rt * 16 + lr;
      int ga = (ks * 4 + lg) ^ (arow & 7);
      af[rt] = *(const short8*)&Al[arow * 128 + ga * 8];
    }
#pragma unroll
    for (int ct = 0; ct < 8; ++ct) {
      int col = ct * 16 + lr;
      int gb = (ks * 4 + lg) ^ (col & 7);
      short8 bf = *(const short8*)&Wl[col * 128 + gb * 8];
#pragma unroll
      for (int rt = 0; rt < 2; ++rt)
        acc[rt][ct] = __builtin_amdgcn_mfma_f32_16x16x32_bf16(af[rt], bf, acc[rt][ct], 0, 0, 0);
    }
  }

#pragma unroll
  for (int rt = 0; rt < 2; ++rt)
#pragma unroll
    for (int r = 0; r < 4; ++r) {
      int row = r0 + w * 32 + rt * 16 + lg * 4 + r;
      bool ok = row < NN;  // uniform across the 16-lane lr group
      float v[8];
#pragma unroll
      for (int ct = 0; ct < 8; ++ct) {
        int col = ct * 16 + lr;
        float vv = acc[rt][ct][r];
        if (BIAS) vv += bias[col];
        if (GELU) vv = gelu_tanh(vv);
        if (RESID) vv += ok ? resid[(size_t)row * 128 + col] : 0.f;
        v[ct] = vv;
      }
      if (RESID || LNF) {
        if (ok)
#pragma unroll
          for (int ct = 0; ct < 8; ++ct)
            ((float*)outp)[(size_t)row * 128 + ct * 16 + lr] = v[ct];
      } else {
        if (ok)
#pragma unroll
          for (int ct = 0; ct < 8; ++ct)
            ((ushort*)outp)[(size_t)row * 128 + ct * 16 + lr] = f2bf(v[ct]);
      }
      if (LNF) {
        float s = 0.f, ss = 0.f;
#pragma unroll
        for (int ct = 0; ct < 8; ++ct) {
          s += v[ct];
          ss = fmaf(v[ct], v[ct], ss);
        }
#pragma unroll
        for (int msk = 8; msk >= 1; msk >>= 1) {
          s += __shfl_xor(s, msk);
          ss += __shfl_xor(ss, msk);
        }
        float mean = s * (1.0f / DDIM);
        float var = ss * (1.0f / DDIM) - mean * mean;
        float inv = rsqrtf(var + 1e-5f);
        if (ok)
#pragma unroll
          for (int ct = 0; ct < 8; ++ct) {
            int col = ct * 16 + lr;
            lnout[(size_t)row * 128 + col] =
                f2bf((v[ct] - mean) * inv * lng[col] + lnb[col]);
          }
      }
    }
}

// ---------------- qe precompute: qe[n][j][h] ----------------

__global__ __launch_bounds__(256) void k_qe(const ushort* __restrict__ qnb,
                                            const float* __restrict__ We,
                                            ushort* __restrict__ qe) {
  __shared__ float Wlds[NRAD][DDIM + 1];
  __shared__ float qlds[4][DDIM];
  int tid = threadIdx.x;
  for (int i = tid; i < NRAD * DDIM; i += 256) Wlds[i / DDIM][i % DDIM] = We[i];
  __syncthreads();
  int w = tid >> 6, t = tid & 63;
  for (int rep = 0; rep < 2; ++rep) {
    int n = blockIdx.x * 8 + rep * 4 + w;
    uint qu = *(const uint*)&qnb[(size_t)n * DDIM + 2 * t];
    qlds[w][2 * t] = bfl(qu);
    qlds[w][2 * t + 1] = bfh(qu);
    if (t < NRAD) {
      float e0 = 0.f, e1 = 0.f, e2 = 0.f, e3 = 0.f;
#pragma unroll
      for (int d = 0; d < 32; ++d) e0 = fmaf(Wlds[t][d], qlds[w][d], e0);
#pragma unroll
      for (int d = 32; d < 64; ++d) e1 = fmaf(Wlds[t][d], qlds[w][d], e1);
#pragma unroll
      for (int d = 64; d < 96; ++d) e2 = fmaf(Wlds[t][d], qlds[w][d], e2);
#pragma unroll
      for (int d = 96; d < 128; ++d) e3 = fmaf(Wlds[t][d], qlds[w][d], e3);
      ushort4 o = {f2bf(e0), f2bf(e1), f2bf(e2), f2bf(e3)};
      *(ushort4*)&qe[(size_t)n * (NRAD * 4) + 4 * t] = o;
    }
  }
}

// ---------------- fused attention v4: near/far split CSR, butterfly softmax ----------------
// wave per node; lane t owns dims 2t,2t+1 (head h=t>>4). Near edges [start,nend),
// far edges [nend,end). shfl_xor butterfly leaves head-sum in every lane.

__device__ __forceinline__ float rbf_fill(float d, int j) {
  const float step = CUTF / (NRAD - 1);
  const float gamma = (NRAD / CUTF) * (NRAD / CUTF);
  float mu = j * step;
  float dm = d - mu;
  float env = 0.5f * (__cosf(PI_F * d / CUTF) + 1.0f);
  return __expf(-gamma * dm * dm) * env;
}

#define SCALE_QK 0.17677669529663687f

__global__ __launch_bounds__(256) void k_attn4(
    const ushort* __restrict__ qnb, const ushort* __restrict__ knb,
    const ushort* __restrict__ vnb, const ushort* __restrict__ qe,
    const int2* __restrict__ er, const int* __restrict__ rowptr,
    const int* __restrict__ nearend, const float* __restrict__ We,
    ushort* __restrict__ msgb) {
  __shared__ float qel[4][64][4];   // [wave][j][head]; reused for arbn in epilogue
  __shared__ float rbl[4][64];
  __shared__ ushort Wel[NRAD * DDIM];
  const int tid = threadIdx.x;
  for (int i = tid; i < NRAD * DDIM; i += 256) Wel[i] = f2bf(We[i]);
  __syncthreads();

  const int w = tid >> 6, t = tid & 63;
  const int n = blockIdx.x * 4 + w;
  const int h = t >> 4;
  const int j0 = t & 15;
  uint qu = *(const uint*)&qnb[(size_t)n * DDIM + 2 * t];
  const float q0 = bfl(qu), q1 = bfh(qu);
  if (t < NRAD) {
    ushort4 qv = *(const ushort4*)&qe[(size_t)n * (NRAD * 4) + 4 * t];
    qel[w][t][0] = bfl(qv.x);
    qel[w][t][1] = bfl(qv.y);
    qel[w][t][2] = bfl(qv.z);
    qel[w][t][3] = bfl(qv.w);
  } else {
    qel[w][t][0] = 0.f; qel[w][t][1] = 0.f; qel[w][t][2] = 0.f; qel[w][t][3] = 0.f;
  }
  const int start = rowptr[n], nend = nearend[n], end = rowptr[n + 1];

  float s = 0.f, a0 = 0.f, a1 = 0.f;
  float4 arb = {0.f, 0.f, 0.f, 0.f};

  // ---- near loop (radial features active) ----
  for (int cb = start; cb < nend; cb += 64) {
    int cnt = min(nend - cb, 64);
    int2 e_t = make_int2(0, 0);
    if (t < cnt) e_t = er[cb + t];
    for (int i = 0; i < cnt; ++i) {
      int src = __shfl(e_t.x, i);
      float dd = __shfl(__int_as_float(e_t.y), i);
      uint ku = *(const uint*)&knb[(size_t)src * DDIM + 2 * t];
      uint vu = *(const uint*)&vnb[(size_t)src * DDIM + 2 * t];
      float pr = q0 * bfl(ku) + q1 * bfh(ku);
      float rb = (t < NRAD) ? rbf_fill(dd, t) : 0.f;
      rbl[w][t] = rb;
      pr = fmaf(rbl[w][j0], qel[w][j0][h], pr);
      pr = fmaf(rbl[w][j0 + 16], qel[w][j0 + 16][h], pr);
      pr = fmaf(rbl[w][j0 + 32], qel[w][j0 + 32][h], pr);
      pr = fmaf(rbl[w][j0 + 48], qel[w][j0 + 48][h], pr);
      pr += __shfl_xor(pr, 1);
      pr += __shfl_xor(pr, 2);
      pr += __shfl_xor(pr, 4);
      pr += __shfl_xor(pr, 8);
      float ae = __expf(fminf(pr * SCALE_QK, 60.f));
      s += ae;
      a0 = fmaf(ae, bfl(vu), a0);
      a1 = fmaf(ae, bfh(vu), a1);
      float aex = __shfl(ae, 0);
      float aey = __shfl(ae, 16);
      float aez = __shfl(ae, 32);
      float aew = __shfl(ae, 48);
      arb.x = fmaf(rb, aex, arb.x);
      arb.y = fmaf(rb, aey, arb.y);
      arb.z = fmaf(rb, aez, arb.z);
      arb.w = fmaf(rb, aew, arb.w);
    }
  }

  // ---- far loop (no radial), 2-edge unrolled for ILP ----
  float s1 = 0.f, b0 = 0.f, b1 = 0.f;
  for (int cb = nend; cb < end; cb += 64) {
    int cnt = min(end - cb, 64);
    int src_t = 0;
    if (t < cnt) src_t = er[cb + t].x;
    int i = 0;
    for (; i + 2 <= cnt; i += 2) {
      int sA = __shfl(src_t, i);
      int sB = __shfl(src_t, i + 1);
      uint kuA = *(const uint*)&knb[(size_t)sA * DDIM + 2 * t];
      uint kuB = *(const uint*)&knb[(size_t)sB * DDIM + 2 * t];
      uint vuA = *(const uint*)&vnb[(size_t)sA * DDIM + 2 * t];
      uint vuB = *(const uint*)&vnb[(size_t)sB * DDIM + 2 * t];
      float pA = q0 * bfl(kuA) + q1 * bfh(kuA);
      float pB = q0 * bfl(kuB) + q1 * bfh(kuB);
      pA += __shfl_xor(pA, 1);
      pB += __shfl_xor(pB, 1);
      pA += __shfl_xor(pA, 2);
      pB += __shfl_xor(pB, 2);
      pA += __shfl_xor(pA, 4);
      pB += __shfl_xor(pB, 4);
      pA += __shfl_xor(pA, 8);
      pB += __shfl_xor(pB, 8);
      float aeA = __expf(fminf(pA * SCALE_QK, 60.f));
      float aeB = __expf(fminf(pB * SCALE_QK, 60.f));
      s += aeA;
      s1 += aeB;
      a0 = fmaf(aeA, bfl(vuA), a0);
      b0 = fmaf(aeB, bfl(vuB), b0);
      a1 = fmaf(aeA, bfh(vuA), a1);
      b1 = fmaf(aeB, bfh(vuB), b1);
    }
    if (i < cnt) {
      int sA = __shfl(src_t, i);
      uint kuA = *(const uint*)&knb[(size_t)sA * DDIM + 2 * t];
      uint vuA = *(const uint*)&vnb[(size_t)sA * DDIM + 2 * t];
      float pA = q0 * bfl(kuA) + q1 * bfh(kuA);
      pA += __shfl_xor(pA, 1);
      pA += __shfl_xor(pA, 2);
      pA += __shfl_xor(pA, 4);
      pA += __shfl_xor(pA, 8);
      float aeA = __expf(fminf(pA * SCALE_QK, 60.f));
      s += aeA;
      a0 = fmaf(aeA, bfl(vuA), a0);
      a1 = fmaf(aeA, bfh(vuA), a1);
    }
  }
  s += s1;
  a0 += b0;
  a1 += b1;

  // ---- finalize: normalize; msg = a_norm + (arb_norm @ We) ----
  float4 s4 = {__shfl(s, 0), __shfl(s, 16), __shfl(s, 32), __shfl(s, 48)};
  float4 inv4 = {1.f / (s4.x + 1e-9f), 1.f / (s4.y + 1e-9f),
                 1.f / (s4.z + 1e-9f), 1.f / (s4.w + 1e-9f)};
  float invo = 1.f / (s + 1e-9f);
  if (t < NRAD) {
    qel[w][t][0] = arb.x * inv4.x;
    qel[w][t][1] = arb.y * inv4.y;
    qel[w][t][2] = arb.z * inv4.z;
    qel[w][t][3] = arb.w * inv4.w;
  }
  a0 *= invo;
  a1 *= invo;
#pragma unroll 10
  for (int j = 0; j < NRAD; ++j) {
    float ar = qel[w][j][h];
    uint wu = *(const uint*)&Wel[j * DDIM + 2 * t];
    a0 = fmaf(ar, bfl(wu), a0);
    a1 = fmaf(ar, bfh(wu), a1);
  }
  uint pk = (uint)f2bf(a0) | ((uint)f2bf(a1) << 16);
  *(uint*)&msgb[(size_t)n * DDIM + 2 * t] = pk;
}

// ---------------- graph sum (batch is sorted): 32 nodes/block, boundary atomics ----------------

#define GS_NODES 32
__global__ void k_graphsum(const float* __restrict__ x, const int* __restrict__ batch,
                           float* __restrict__ g) {
  int t = threadIdx.x;  // 128 dims
  int n0 = blockIdx.x * GS_NODES;
  int nend = n0 + GS_NODES;
  if (nend > NN) nend = NN;
  if (n0 >= NN) return;
  float acc = 0.f;
  int cur = batch[n0];
  for (int n = n0; n < nend; ++n) {
    int bb = batch[n];
    if (bb != cur) {
      atomicAdd(&g[(size_t)cur * DDIM + t], acc);
      acc = 0.f;
      cur = bb;
    }
    acc += x[(size_t)n * DDIM + t];
  }
  atomicAdd(&g[(size_t)cur * DDIM + t], acc);
}

// ---------------- output projection ----------------

__global__ void k_out(const float* __restrict__ g, const float* __restrict__ W,
                      const float* __restrict__ b, float* __restrict__ out) {
  int idx = blockIdx.x * blockDim.x + threadIdx.x;
  if (idx >= NGRAPH * DOUT) return;
  int r = idx / DOUT, c = idx % DOUT;
  float acc = b[c];
#pragma unroll 8
  for (int k = 0; k < DDIM; ++k) acc = fmaf(g[r * DDIM + k], W[k * DOUT + c], acc);
  out[idx] = acc;
}

// ---------------- launch ----------------

extern "C" void kernel_launch(void* const* d_in, const int* in_sizes, int n_in,
                              void* d_out, int out_size, void* d_ws, size_t ws_size,
                              hipStream_t stream) {
  const float* pos = (const float*)d_in[0];
  const int* at = (const int*)d_in[1];
  const int* ei = (const int*)d_in[2];
  const int* batch = (const int*)d_in[3];
  const float* emb = (const float*)d_in[4];
  const float* W_init = (const float*)d_in[5];
  const float* b_init = (const float*)d_in[6];
  const float* Wq = (const float*)d_in[7];
  const float* Wk = (const float*)d_in[8];
  const float* Wv = (const float*)d_in[9];
  const float* We = (const float*)d_in[10];
  const float* Wo = (const float*)d_in[11];
  const float* Wm1 = (const float*)d_in[12];
  const float* bm1 = (const float*)d_in[13];
  const float* Wm2 = (const float*)d_in[14];
  const float* bm2 = (const float*)d_in[15];
  const float* ln_g = (const float*)d_in[16];
  const float* ln_b = (const float*)d_in[17];
  const float* W_out = (const float*)d_in[18];
  const float* b_out = (const float*)d_in[19];
  float* out = (float*)d_out;

  const size_t ND = (size_t)NN * DDIM;  // 6.4M
  float* x = (float*)d_ws;              // f32 ND
  ushort* qnb = (ushort*)(x + ND);      // bf16 ND (alias hb)
  ushort* knb = qnb + ND;               // bf16 ND (alias h2)
  ushort* vnb = knb + ND;               // bf16 ND
  ushort* msgb = vnb + ND;              // bf16 ND
  ushort* qe = msgb + ND;               // bf16 NN*200
  ushort* Wtb = qe + (size_t)NN * 200;  // bf16 12*16384
  float* de = (float*)(Wtb + 12 * 16384);  // f32 NE
  int* deg = (int*)(de + NE);
  int* cnear = deg + NN;
  int* cfar = cnear + NN;
  int* rowptr = cfar + NN;
  int2* er = (int2*)(rowptr + NN + 64);  // NE int2
  float* gb = (float*)(er + NE);         // NG*DDIM
  int* bsum = (int*)(gb + NGRAPH * DDIM);  // SCAN_N
  // total ~96 MB

  ushort* hb = qnb;
  ushort* h2 = knb;

  k_wconv<<<12 * 16384 / 256, 256, 0, stream>>>(Wq, Wk, Wv, Wo, Wm1, Wm2, Wtb);
  k_fill_i<<<(NN + 255) / 256, 256, 0, stream>>>(deg, 0, NN);
  k_init<<<(NN * DDIM + 255) / 256, 256, 0, stream>>>(pos, at, emb, W_init, b_init, x);
  k_edge<<<(NE + 255) / 256, 256, 0, stream>>>(pos, ei, de, deg);
  k_scan1<<<SCAN_N, 256, 0, stream>>>(deg, bsum);
  k_scan2<<<1, 256, 0, stream>>>(bsum);
  k_scan3<<<SCAN_N, 256, 0, stream>>>(deg, bsum, rowptr, cnear, cfar);
  k_scatter<<<(NE + 255) / 256, 256, 0, stream>>>(ei, de, cnear, cfar, er);

  const int gg = (NN + 127) / 128;  // 391
  for (int l = 0; l < 2; ++l) {
    const ushort* Wt_l = Wtb + (size_t)l * 6 * 16384;
    const float* We_l = We + (size_t)l * NRAD * DDIM;

    k_qkv<<<gg, 256, 0, stream>>>(x, Wt_l, qnb, knb, vnb);
    k_qe<<<NN / 8, 256, 0, stream>>>(qnb, We_l, qe);
    k_attn4<<<NN / 4, 256, 0, stream>>>(qnb, knb, vnb, qe, er, rowptr, cnear, We_l, msgb);

    // x += msg@Wo, fused layernorm -> hb
    k_gemm2<false, false, true, true><<<gg, 256, 0, stream>>>(
        msgb, Wt_l + 3 * 16384, nullptr, x, x,
        ln_g + (size_t)l * DDIM, ln_b + (size_t)l * DDIM, hb);
    // h2 = gelu(hb@Wm1 + bm1)
    k_gemm2<true, true, false, false><<<gg, 256, 0, stream>>>(
        hb, Wt_l + 4 * 16384, bm1 + (size_t)l * DDIM, nullptr, h2, nullptr, nullptr, nullptr);
    // x += h2@Wm2 + bm2
    k_gemm2<true, false, true, false><<<gg, 256, 0, stream>>>(
        h2, Wt_l + 5 * 16384, bm2 + (size_t)l * DDIM, x, x, nullptr, nullptr, nullptr);
  }

  k_fill_f<<<(NGRAPH * DDIM + 255) / 256, 256, 0, stream>>>(gb, 0.f, NGRAPH * DDIM);
  k_graphsum<<<(NN + GS_NODES - 1) / GS_NODES, 128, 0, stream>>>(x, batch, gb);
  k_out<<<(NGRAPH * DOUT + 255) / 256, 256, 0, stream>>>(gb, W_out, b_out, out);
}